// Round 1
// baseline (533.555 us; speedup 1.0000x reference)
//
#include <hip/hip_runtime.h>

#define B_   2
#define N_   512
#define DM_  1024
#define H_   16
#define LAM_ 0.1f

// ---------------------------------------------------------------------------
// argmax(depth_logits) -> ws int (jnp.argmax semantics: first max wins)
// ---------------------------------------------------------------------------
__global__ void k_select(const float* __restrict__ logits, int* __restrict__ sel) {
    if (threadIdx.x == 0) {
        float best = logits[0];
        int bi = 0;
        for (int i = 1; i < 4; ++i) {
            float v = logits[i];
            if (v > best) { best = v; bi = i; }
        }
        *sel = bi;
    }
}

// ---------------------------------------------------------------------------
// Stage 1: qkv = einsum('bnds,dse->bnde', x.reshape+pe, wqkv)
// Tiled f32 GEMM per (b,d): [N, ds] @ [ds, 3ds]. Block (16,16), 16x64 tile.
// Epilogue scatters into Q/K/V with layout [B, D, H, N, hd] (per-(b,d,h)
// slices contiguous for the attention stage).
// ---------------------------------------------------------------------------
template<int D>
__global__ __launch_bounds__(256) void k_qkv(
        const int* __restrict__ sel, int branch,
        const float* __restrict__ x, const float* __restrict__ pe,
        const float* __restrict__ wqkv,
        float* __restrict__ Q, float* __restrict__ K, float* __restrict__ V) {
    if (*sel != branch) return;
    constexpr int ds = DM_ / D;
    constexpr int hd = ds / H_;

    __shared__ float As[16][17];
    __shared__ float Ws[16][65];

    const int tx = threadIdx.x, ty = threadIdx.y;
    const int b = blockIdx.z / D, d = blockIdx.z % D;
    const int row0 = blockIdx.y * 16;
    const int col0 = blockIdx.x * 64;

    const float* xb  = x  + (size_t)b * N_ * DM_ + d * ds;  // row stride DM_
    const float* peb = pe + d * ds;                          // row stride DM_ (pe is [N, D, ds] = [N, DM])
    const float* wb  = wqkv + (size_t)d * ds * (3 * ds);

    float acc[4] = {0.f, 0.f, 0.f, 0.f};

    for (int k0 = 0; k0 < ds; k0 += 16) {
        const int n = row0 + ty;
        As[ty][tx] = xb[(size_t)n * DM_ + k0 + tx] + peb[(size_t)n * DM_ + k0 + tx];
        #pragma unroll
        for (int c = 0; c < 4; ++c)
            Ws[ty][tx + 16 * c] = wb[(size_t)(k0 + ty) * (3 * ds) + col0 + tx + 16 * c];
        __syncthreads();
        #pragma unroll
        for (int kk = 0; kk < 16; ++kk) {
            const float a = As[ty][kk];
            acc[0] += a * Ws[kk][tx];
            acc[1] += a * Ws[kk][tx + 16];
            acc[2] += a * Ws[kk][tx + 32];
            acc[3] += a * Ws[kk][tx + 48];
        }
        __syncthreads();
    }

    const int n = row0 + ty;
    #pragma unroll
    for (int c = 0; c < 4; ++c) {
        const int e    = col0 + tx + 16 * c;
        const int part = e / ds;
        const int ep   = e % ds;
        const int h    = ep / hd;
        const int t    = ep % hd;
        float* dst = (part == 0) ? Q : (part == 1) ? K : V;
        dst[((((size_t)b * D + d) * H_ + h) * N_ + n) * hd + t] = acc[c];
    }
}

// ---------------------------------------------------------------------------
// Stage 2: fused attention. One block per (b, d, h, row-tile of D rows):
// grid (N/D, D*H, B) -> constant 16384 blocks per branch.
// Two-pass row softmax with ring bias; scores live in LDS (never hit HBM).
// Output layout O: [B, N, D, ds] (ready for the depth-mix stage).
// ---------------------------------------------------------------------------
template<int D>
__global__ __launch_bounds__(256) void k_attn(
        const int* __restrict__ sel, int branch,
        const float* __restrict__ Q, const float* __restrict__ K,
        const float* __restrict__ V, float* __restrict__ O) {
    if (*sel != branch) return;
    constexpr int ds = DM_ / D;
    constexpr int hd = ds / H_;   // 64,32,16,8
    constexpr int G  = 256 / hd;  // PV partial-sum groups

    const int h = blockIdx.y % H_;
    const int d = blockIdx.y / H_;
    const int b = blockIdx.z;
    const size_t base = ((((size_t)b * D + d) * H_ + h) * N_) * (size_t)hd;
    const float* Qb = Q + base;
    const float* Kb = K + base;
    const float* Vb = V + base;

    __shared__ float qs[64];
    __shared__ float sc[N_];
    __shared__ float red[8];
    __shared__ float ps[256];

    const int tid = threadIdx.x;
    const float scale = rsqrtf((float)hd);

    for (int r = 0; r < D; ++r) {
        const int n = blockIdx.x * D + r;

        if (tid < hd) qs[tid] = Qb[(size_t)n * hd + tid];
        __syncthreads();

        float lmax = -1e30f;
        for (int j = tid; j < N_; j += 256) {
            float dot = 0.f;
            #pragma unroll
            for (int t = 0; t < hd; ++t) dot += qs[t] * Kb[(size_t)j * hd + t];
            int df = n - j; if (df < 0) df = -df;
            const int ring = (df < N_ - df) ? df : (N_ - df);
            const float s = dot * scale - LAM_ * (2.0f / N_) * (float)ring;
            sc[j] = s;
            lmax = fmaxf(lmax, s);
        }
        #pragma unroll
        for (int o = 32; o; o >>= 1) lmax = fmaxf(lmax, __shfl_down(lmax, o, 64));
        if ((tid & 63) == 0) red[tid >> 6] = lmax;
        __syncthreads();
        const float mx = fmaxf(fmaxf(red[0], red[1]), fmaxf(red[2], red[3]));

        float lsum = 0.f;
        for (int j = tid; j < N_; j += 256) {
            const float p = __expf(sc[j] - mx);
            sc[j] = p;
            lsum += p;
        }
        #pragma unroll
        for (int o = 32; o; o >>= 1) lsum += __shfl_down(lsum, o, 64);
        if ((tid & 63) == 0) red[4 + (tid >> 6)] = lsum;
        __syncthreads();
        const float inv = 1.0f / (red[4] + red[5] + red[6] + red[7]);

        // PV: thread = (g, t); group g sums a strided subset of rows
        const int t = tid % hd, g = tid / hd;
        float part = 0.f;
        for (int j = g; j < N_; j += G) part += sc[j] * Vb[(size_t)j * hd + t];
        ps[tid] = part;
        __syncthreads();
        if (tid < hd) {
            float o = 0.f;
            #pragma unroll
            for (int gg = 0; gg < G; ++gg) o += ps[gg * hd + tid];
            O[(((size_t)b * N_ + n) * D + d) * ds + h * hd + tid] = o * inv;
        }
        __syncthreads();
    }
}

// ---------------------------------------------------------------------------
// Stage 3: low-rank depth fusion. mix = fu@fv [D,D] (computed in LDS),
// F[b,n,d,s] = sum_f mix[d,f] * O[b,n,f,s]. Elementwise-cheap.
// ---------------------------------------------------------------------------
template<int D>
__global__ __launch_bounds__(256) void k_mix(
        const int* __restrict__ sel, int branch,
        const float* __restrict__ fu, const float* __restrict__ fv,
        const float* __restrict__ O, float* __restrict__ F) {
    if (*sel != branch) return;
    constexpr int ds = DM_ / D;
    constexpr int R  = (D / 4 > 0) ? (D / 4) : 1;

    __shared__ float mix[D][D];
    const int tid = threadIdx.x;
    if (tid < D * D) {
        const int d = tid / D, f = tid % D;
        float m = 0.f;
        #pragma unroll
        for (int rr = 0; rr < R; ++rr) m += fu[d * R + rr] * fv[rr * D + f];
        mix[d][f] = m;
    }
    __syncthreads();

    const size_t idx = (size_t)blockIdx.x * 256 + tid;  // over B*N*DM
    const int dm = (int)(idx % DM_);
    const size_t bn = idx / DM_;
    const int d = dm / ds, s = dm % ds;
    const float* Ob = O + bn * DM_ + s;
    float acc = 0.f;
    #pragma unroll
    for (int f = 0; f < D; ++f) acc += mix[d][f] * Ob[(size_t)f * ds];
    F[idx] = acc;
}

// ---------------------------------------------------------------------------
// Stage 4: out = F @ wo   ([B*N=1024, DM] @ [DM, DM])
// ---------------------------------------------------------------------------
__global__ __launch_bounds__(256) void k_wo(
        const int* __restrict__ sel, int branch,
        const float* __restrict__ F, const float* __restrict__ W,
        float* __restrict__ out) {
    if (*sel != branch) return;

    __shared__ float As[16][17];
    __shared__ float Ws[16][65];

    const int tx = threadIdx.x, ty = threadIdx.y;
    const int row0 = blockIdx.y * 16;
    const int col0 = blockIdx.x * 64;

    float acc[4] = {0.f, 0.f, 0.f, 0.f};

    for (int k0 = 0; k0 < DM_; k0 += 16) {
        As[ty][tx] = F[(size_t)(row0 + ty) * DM_ + k0 + tx];
        #pragma unroll
        for (int c = 0; c < 4; ++c)
            Ws[ty][tx + 16 * c] = W[(size_t)(k0 + ty) * DM_ + col0 + tx + 16 * c];
        __syncthreads();
        #pragma unroll
        for (int kk = 0; kk < 16; ++kk) {
            const float a = As[ty][kk];
            acc[0] += a * Ws[kk][tx];
            acc[1] += a * Ws[kk][tx + 16];
            acc[2] += a * Ws[kk][tx + 32];
            acc[3] += a * Ws[kk][tx + 48];
        }
        __syncthreads();
    }
    #pragma unroll
    for (int c = 0; c < 4; ++c)
        out[(size_t)(row0 + ty) * DM_ + col0 + tx + 16 * c] = acc[c];
}

// ---------------------------------------------------------------------------
// launch helpers
// ---------------------------------------------------------------------------
template<int D>
static void launch_branch(int bi, void* const* d_in, const int* sel,
                          const float* x, float* Q, float* K, float* V,
                          float* O, float* F, float* out, hipStream_t stream) {
    constexpr int ds = DM_ / D;
    const float* pe   = (const float*)d_in[2 + 5 * bi];
    const float* wqkv = (const float*)d_in[3 + 5 * bi];
    const float* wo   = (const float*)d_in[4 + 5 * bi];
    const float* fu   = (const float*)d_in[5 + 5 * bi];
    const float* fv   = (const float*)d_in[6 + 5 * bi];

    k_qkv<D><<<dim3(3 * ds / 64, N_ / 16, B_ * D), dim3(16, 16), 0, stream>>>(
        sel, bi, x, pe, wqkv, Q, K, V);
    k_attn<D><<<dim3(N_ / D, D * H_, B_), dim3(256), 0, stream>>>(
        sel, bi, Q, K, V, O);
    k_mix<D><<<dim3(B_ * N_ * DM_ / 256), dim3(256), 0, stream>>>(
        sel, bi, fu, fv, O, F);
    k_wo<<<dim3(DM_ / 64, B_ * N_ / 16), dim3(16, 16), 0, stream>>>(
        sel, bi, F, wo, out);
}

extern "C" void kernel_launch(void* const* d_in, const int* in_sizes, int n_in,
                              void* d_out, int out_size, void* d_ws, size_t ws_size,
                              hipStream_t stream) {
    const float* x      = (const float*)d_in[0];
    const float* logits = (const float*)d_in[1];
    float* out = (float*)d_out;

    int* sel = (int*)d_ws;
    const size_t CNT = (size_t)B_ * N_ * DM_;  // 1M floats = 4 MB
    float* Q = (float*)((char*)d_ws + 256);
    float* K = Q + CNT;
    float* V = K + CNT;
    float* O = V + CNT;
    float* F = O + CNT;

    k_select<<<1, 64, 0, stream>>>(logits, sel);

    launch_branch<1>(0, d_in, sel, x, Q, K, V, O, F, out, stream);
    launch_branch<2>(1, d_in, sel, x, Q, K, V, O, F, out, stream);
    launch_branch<4>(2, d_in, sel, x, Q, K, V, O, F, out, stream);
    launch_branch<8>(3, d_in, sel, x, Q, K, V, O, F, out, stream);
}

// Round 2
// 417.250 us; speedup vs baseline: 1.2787x; 1.2787x over previous
//
#include <hip/hip_runtime.h>

#define B_   2
#define N_   512
#define DM_  1024
#define H_   16
#define LAM_ 0.1f

typedef __attribute__((ext_vector_type(8))) short bf16x8;
typedef __attribute__((ext_vector_type(4))) float f32x4;
typedef unsigned short ush;

__device__ inline ush f2bf(float v) {
    union { float f; unsigned u; } c; c.f = v;
    unsigned r = c.u + 0x7FFF + ((c.u >> 16) & 1);
    return (ush)(r >> 16);
}
__device__ inline float bf2f(ush b) {
    union { float f; unsigned u; } c; c.u = ((unsigned)b) << 16; return c.f;
}
__device__ inline f32x4 mfma16(bf16x8 a, bf16x8 b, f32x4 c) {
    return __builtin_amdgcn_mfma_f32_16x16x32_bf16(a, b, c, 0, 0, 0);
}
__device__ inline float redmax8(float v) {
    v = fmaxf(v, __shfl_xor(v, 1)); v = fmaxf(v, __shfl_xor(v, 2));
    return fmaxf(v, __shfl_xor(v, 4));
}
__device__ inline float redsum8(float v) {
    v += __shfl_xor(v, 1); v += __shfl_xor(v, 2); return v + __shfl_xor(v, 4);
}

// ---------------------------------------------------------------------------
__global__ void k_select(const float* __restrict__ logits, int* __restrict__ sel) {
    if (threadIdx.x == 0) {
        float best = logits[0]; int bi = 0;
        for (int i = 1; i < 4; ++i) { float v = logits[i]; if (v > best) { best = v; bi = i; } }
        *sel = bi;
    }
}

// ---------------------------------------------------------------------------
// prep: xs = x + pe -> bf16 hi/lo   (pe flat [N, DM] regardless of D)
// ---------------------------------------------------------------------------
__global__ __launch_bounds__(256) void k_prep_x(
        const int* __restrict__ sel, const float* __restrict__ x,
        const float* __restrict__ pe0, const float* __restrict__ pe1,
        const float* __restrict__ pe2, const float* __restrict__ pe3,
        ush* __restrict__ xh, ush* __restrict__ xl) {
    const int s = *sel;
    const float* pe = (s == 0) ? pe0 : (s == 1) ? pe1 : (s == 2) ? pe2 : pe3;
    const size_t i = (size_t)blockIdx.x * 256 + threadIdx.x;
    const float v = x[i] + pe[i % ((size_t)N_ * DM_)];
    const ush h = f2bf(v);
    xh[i] = h; xl[i] = f2bf(v - bf2f(h));
}

// ---------------------------------------------------------------------------
// prep: wqkv [D, ds, 3ds] -> transposed bf16 hi/lo  wt[d][e][s]
// ---------------------------------------------------------------------------
template<int D>
__device__ void prep_w_body(size_t i, const float* __restrict__ w,
                            ush* __restrict__ wh, ush* __restrict__ wl) {
    constexpr int ds = DM_ / D;
    constexpr size_t TOT = (size_t)D * ds * 3 * ds;
    if (i >= TOT) return;
    const int per = ds * 3 * ds;
    const int d = (int)(i / per), rem = (int)(i % per);
    const int s = rem / (3 * ds), e = rem % (3 * ds);
    const float v = w[i];
    const size_t o = (size_t)d * 3 * ds * ds + (size_t)e * ds + s;
    const ush h = f2bf(v);
    wh[o] = h; wl[o] = f2bf(v - bf2f(h));
}
__global__ __launch_bounds__(256) void k_prep_w(
        const int* __restrict__ sel,
        const float* __restrict__ w0, const float* __restrict__ w1,
        const float* __restrict__ w2, const float* __restrict__ w3,
        ush* __restrict__ wh, ush* __restrict__ wl) {
    const size_t i = (size_t)blockIdx.x * 256 + threadIdx.x;
    switch (*sel) {
        case 0: prep_w_body<1>(i, w0, wh, wl); break;
        case 1: prep_w_body<2>(i, w1, wh, wl); break;
        case 2: prep_w_body<4>(i, w2, wh, wl); break;
        case 3: prep_w_body<8>(i, w3, wh, wl); break;
    }
}

// ---------------------------------------------------------------------------
// prep: wo [DM, DM] -> transposed bf16 hi/lo  wot[j][k] = wo[k][j]
// ---------------------------------------------------------------------------
__global__ __launch_bounds__(256) void k_prep_wo(
        const int* __restrict__ sel,
        const float* __restrict__ w0, const float* __restrict__ w1,
        const float* __restrict__ w2, const float* __restrict__ w3,
        ush* __restrict__ wh, ush* __restrict__ wl) {
    const int s = *sel;
    const float* w = (s == 0) ? w0 : (s == 1) ? w1 : (s == 2) ? w2 : w3;
    const size_t i = (size_t)blockIdx.x * 256 + threadIdx.x;
    const int k = (int)(i / DM_), j = (int)(i % DM_);
    const float v = w[i];
    const size_t o = (size_t)j * DM_ + k;
    const ush h = f2bf(v);
    wh[o] = h; wl[o] = f2bf(v - bf2f(h));
}

// ---------------------------------------------------------------------------
// Split-bf16 MFMA GEMM core: 64x64 tile, BK=32, 4 waves (2x2 quadrants).
// A [64][32] bf16 hi/lo, Bt [64cols][32k] bf16 hi/lo in LDS, row stride 40.
// acc += Ah*Bh + Al*Bh + Ah*Bl  (lo*lo dropped: ~2^-18 rel error)
// ---------------------------------------------------------------------------
template<int KD>
__device__ void gemm_core(const ush* __restrict__ Ah, const ush* __restrict__ Al, int lda,
                          const ush* __restrict__ Bh, const ush* __restrict__ Bl, int ldb,
                          int row0, int col0, int tid, ush* lds, f32x4 acc[2][2]) {
    ush* lAh = lds; ush* lAl = lds + 2560; ush* lBh = lds + 5120; ush* lBl = lds + 7680;
    const int srow = tid >> 2, scg = tid & 3;
    const int lane = tid & 63, w = tid >> 6;
    const int wm = w >> 1, wn = w & 1;
    const int lr = lane & 15, lb = lane >> 4;

    for (int k0 = 0; k0 < KD; k0 += 32) {
        *(bf16x8*)&lAh[srow * 40 + scg * 8] =
            *(const bf16x8*)&Ah[(size_t)(row0 + srow) * lda + k0 + scg * 8];
        *(bf16x8*)&lAl[srow * 40 + scg * 8] =
            *(const bf16x8*)&Al[(size_t)(row0 + srow) * lda + k0 + scg * 8];
        *(bf16x8*)&lBh[srow * 40 + scg * 8] =
            *(const bf16x8*)&Bh[(size_t)(col0 + srow) * ldb + k0 + scg * 8];
        *(bf16x8*)&lBl[srow * 40 + scg * 8] =
            *(const bf16x8*)&Bl[(size_t)(col0 + srow) * ldb + k0 + scg * 8];
        __syncthreads();
        bf16x8 ah[2], al[2], bh[2], bl[2];
        #pragma unroll
        for (int mg = 0; mg < 2; ++mg) {
            const int r = wm * 32 + mg * 16 + lr;
            ah[mg] = *(const bf16x8*)&lAh[r * 40 + lb * 8];
            al[mg] = *(const bf16x8*)&lAl[r * 40 + lb * 8];
        }
        #pragma unroll
        for (int ng = 0; ng < 2; ++ng) {
            const int r = wn * 32 + ng * 16 + lr;
            bh[ng] = *(const bf16x8*)&lBh[r * 40 + lb * 8];
            bl[ng] = *(const bf16x8*)&lBl[r * 40 + lb * 8];
        }
        #pragma unroll
        for (int mg = 0; mg < 2; ++mg)
            #pragma unroll
            for (int ng = 0; ng < 2; ++ng) {
                acc[mg][ng] = mfma16(ah[mg], bh[ng], acc[mg][ng]);
                acc[mg][ng] = mfma16(al[mg], bh[ng], acc[mg][ng]);
                acc[mg][ng] = mfma16(ah[mg], bl[ng], acc[mg][ng]);
            }
        __syncthreads();
    }
}

// ---------------------------------------------------------------------------
// qkv GEMM: per (b,d): [512, ds] @ [ds, 3ds]; scatter into Q/K/V [B,D,H,N,hd]
// 1D grid of 768 blocks (constant across D)
// ---------------------------------------------------------------------------
template<int D>
__device__ void qkv_body(int bid, int tid,
                         const ush* __restrict__ xh, const ush* __restrict__ xl,
                         const ush* __restrict__ wh, const ush* __restrict__ wl,
                         float* __restrict__ Q, float* __restrict__ K,
                         float* __restrict__ V, ush* lds) {
    constexpr int ds = DM_ / D;
    constexpr int hd = ds / H_;
    constexpr int nx = 3 * ds / 64;
    const int bx = bid % nx, by = (bid / nx) & 7, bz = bid / (nx * 8);
    const int b = bz / D, d = bz % D;
    const int row0 = by * 64, col0 = bx * 64;

    f32x4 acc[2][2] = {};
    gemm_core<ds>(xh + (size_t)b * N_ * DM_ + d * ds, xl + (size_t)b * N_ * DM_ + d * ds, DM_,
                  wh + (size_t)d * 3 * ds * ds, wl + (size_t)d * 3 * ds * ds, ds,
                  row0, col0, tid, lds, acc);

    const int lane = tid & 63, w = tid >> 6;
    const int wm = w >> 1, wn = w & 1;
    const int lr = lane & 15, lb = lane >> 4;
    #pragma unroll
    for (int mg = 0; mg < 2; ++mg)
        #pragma unroll
        for (int ng = 0; ng < 2; ++ng)
            #pragma unroll
            for (int i = 0; i < 4; ++i) {
                const int n = row0 + wm * 32 + mg * 16 + lb * 4 + i;
                const int e = col0 + wn * 32 + ng * 16 + lr;
                const int part = e / ds, ep = e % ds;
                const int h = ep / hd, t = ep % hd;
                float* dst = (part == 0) ? Q : (part == 1) ? K : V;
                dst[((((size_t)b * D + d) * H_ + h) * N_ + n) * hd + t] = acc[mg][ng][i];
            }
}
__global__ __launch_bounds__(256) void k_qkv(
        const int* __restrict__ sel,
        const ush* __restrict__ xh, const ush* __restrict__ xl,
        const ush* __restrict__ wh, const ush* __restrict__ wl,
        float* __restrict__ Q, float* __restrict__ K, float* __restrict__ V) {
    __shared__ ush lds[4 * 2560];
    const int bid = blockIdx.x, tid = threadIdx.x;
    switch (*sel) {
        case 0: qkv_body<1>(bid, tid, xh, xl, wh, wl, Q, K, V, lds); break;
        case 1: qkv_body<2>(bid, tid, xh, xl, wh, wl, Q, K, V, lds); break;
        case 2: qkv_body<4>(bid, tid, xh, xl, wh, wl, Q, K, V, lds); break;
        case 3: qkv_body<8>(bid, tid, xh, xl, wh, wl, Q, K, V, lds); break;
    }
}

// ---------------------------------------------------------------------------
// flash attention, f32: 32 Q-rows/block, 8 lanes per row, K-tiles of 64.
// Q in registers, K/V direct from global (L2-resident), P via LDS tile.
// ---------------------------------------------------------------------------
template<int D>
__device__ void attn_body(int bid, int tid, const float* __restrict__ Q,
                          const float* __restrict__ K, const float* __restrict__ V,
                          float* __restrict__ O, float (*sp)[65]) {
    constexpr int ds = DM_ / D;
    constexpr int hd = ds / H_;
    constexpr int CPT = hd / 8;
    constexpr int NB = 16 * D * H_ * B_;
    if (bid >= NB) return;

    const int bx = bid % 16;
    const int rest = bid / 16;
    const int by = rest % (D * H_);
    const int b = rest / (D * H_);
    const int h = by % H_, d = by / H_;

    const int row = tid >> 3, t8 = tid & 7;
    const int n = bx * 32 + row;
    const size_t base = ((((size_t)b * D + d) * H_ + h) * N_) * (size_t)hd;
    const float* Qb = Q + base;
    const float* Kb = K + base;
    const float* Vb = V + base;

    float4 qr[hd / 4];
    {
        const float4* q4 = (const float4*)&Qb[(size_t)n * hd];
        #pragma unroll
        for (int i = 0; i < hd / 4; ++i) qr[i] = q4[i];
    }

    const float scale = rsqrtf((float)hd);
    const float RB = LAM_ * (2.0f / N_);
    float m_run = -1e30f, l_run = 0.f;
    float oacc[CPT];
    #pragma unroll
    for (int i = 0; i < CPT; ++i) oacc[i] = 0.f;
    const int c0 = t8 * CPT;

    for (int kt = 0; kt < N_ / 64; ++kt) {
        float s[8];
        #pragma unroll
        for (int c = 0; c < 8; ++c) {
            const int j = kt * 64 + t8 * 8 + c;
            const float4* k4 = (const float4*)&Kb[(size_t)j * hd];
            float ax = 0.f, ay = 0.f, az = 0.f, aw = 0.f;
            #pragma unroll
            for (int i = 0; i < hd / 4; ++i) {
                const float4 kv = k4[i];
                ax += qr[i].x * kv.x; ay += qr[i].y * kv.y;
                az += qr[i].z * kv.z; aw += qr[i].w * kv.w;
            }
            int df = n - j; if (df < 0) df = -df;
            const int ring = (df < N_ - df) ? df : (N_ - df);
            s[c] = (ax + ay + az + aw) * scale - RB * (float)ring;
        }
        float mt = s[0];
        #pragma unroll
        for (int c = 1; c < 8; ++c) mt = fmaxf(mt, s[c]);
        mt = redmax8(mt);
        const float m_new = fmaxf(m_run, mt);
        const float f = __expf(m_run - m_new);
        float psum = 0.f;
        #pragma unroll
        for (int c = 0; c < 8; ++c) { s[c] = __expf(s[c] - m_new); psum += s[c]; }
        psum = redsum8(psum);
        l_run = l_run * f + psum;
        m_run = m_new;
        #pragma unroll
        for (int i = 0; i < CPT; ++i) oacc[i] *= f;
        #pragma unroll
        for (int c = 0; c < 8; ++c) sp[row][t8 * 8 + c] = s[c];
        __syncthreads();
        for (int j = 0; j < 64; ++j) {
            const float p = sp[row][j];
            const float* vr = &Vb[(size_t)(kt * 64 + j) * hd + c0];
            #pragma unroll
            for (int i = 0; i < CPT; ++i) oacc[i] += p * vr[i];
        }
        __syncthreads();
    }
    const float inv = 1.0f / l_run;
    #pragma unroll
    for (int i = 0; i < CPT; ++i)
        O[((size_t)b * N_ + n) * DM_ + d * ds + h * hd + c0 + i] = oacc[i] * inv;
}
__global__ __launch_bounds__(256) void k_attn(
        const int* __restrict__ sel, const float* __restrict__ Q,
        const float* __restrict__ K, const float* __restrict__ V,
        float* __restrict__ O) {
    __shared__ float sp[32][65];
    const int bid = blockIdx.x, tid = threadIdx.x;
    switch (*sel) {
        case 0: attn_body<1>(bid, tid, Q, K, V, O, sp); break;
        case 1: attn_body<2>(bid, tid, Q, K, V, O, sp); break;
        case 2: attn_body<4>(bid, tid, Q, K, V, O, sp); break;
        case 3: attn_body<8>(bid, tid, Q, K, V, O, sp); break;
    }
}

// ---------------------------------------------------------------------------
// depth mix: F = einsum(mix, O), written as bf16 hi/lo for the wo GEMM
// ---------------------------------------------------------------------------
template<int D>
__device__ void mix_body(int bid, int tid, const float* __restrict__ fu,
                         const float* __restrict__ fv, const float* __restrict__ O,
                         ush* __restrict__ Fh, ush* __restrict__ Fl, float* mixs) {
    constexpr int ds = DM_ / D;
    constexpr int R = (D / 4 > 0) ? (D / 4) : 1;
    if (tid < D * D) {
        const int d = tid / D, f = tid % D;
        float m = 0.f;
        #pragma unroll
        for (int rr = 0; rr < R; ++rr) m += fu[d * R + rr] * fv[rr * D + f];
        mixs[tid] = m;
    }
    __syncthreads();
    const size_t idx = (size_t)bid * 256 + tid;
    const int dm = (int)(idx % DM_);
    const size_t bn = idx / DM_;
    const int d = dm / ds, s0 = dm % ds;
    const float* Ob = O + bn * DM_ + s0;
    float acc = 0.f;
    #pragma unroll
    for (int f = 0; f < D; ++f) acc += mixs[d * D + f] * Ob[(size_t)f * ds];
    const ush hh = f2bf(acc);
    Fh[idx] = hh; Fl[idx] = f2bf(acc - bf2f(hh));
}
__global__ __launch_bounds__(256) void k_mix(
        const int* __restrict__ sel,
        const float* __restrict__ fu0, const float* __restrict__ fv0,
        const float* __restrict__ fu1, const float* __restrict__ fv1,
        const float* __restrict__ fu2, const float* __restrict__ fv2,
        const float* __restrict__ fu3, const float* __restrict__ fv3,
        const float* __restrict__ O, ush* __restrict__ Fh, ush* __restrict__ Fl) {
    __shared__ float mixs[64];
    const int bid = blockIdx.x, tid = threadIdx.x;
    switch (*sel) {
        case 0: mix_body<1>(bid, tid, fu0, fv0, O, Fh, Fl, mixs); break;
        case 1: mix_body<2>(bid, tid, fu1, fv1, O, Fh, Fl, mixs); break;
        case 2: mix_body<4>(bid, tid, fu2, fv2, O, Fh, Fl, mixs); break;
        case 3: mix_body<8>(bid, tid, fu3, fv3, O, Fh, Fl, mixs); break;
    }
}

// ---------------------------------------------------------------------------
// out = F @ wo  (split-bf16 MFMA; branch-independent: ws holds selected data)
// ---------------------------------------------------------------------------
__global__ __launch_bounds__(256) void k_wo(
        const ush* __restrict__ Fh, const ush* __restrict__ Fl,
        const ush* __restrict__ wh, const ush* __restrict__ wl,
        float* __restrict__ out) {
    __shared__ ush lds[4 * 2560];
    const int tid = threadIdx.x;
    const int bx = blockIdx.x % 16, by = blockIdx.x / 16;
    const int row0 = by * 64, col0 = bx * 64;
    f32x4 acc[2][2] = {};
    gemm_core<DM_>(Fh, Fl, DM_, wh, wl, DM_, row0, col0, tid, lds, acc);
    const int lane = tid & 63, w = tid >> 6;
    const int wm = w >> 1, wn = w & 1;
    const int lr = lane & 15, lb = lane >> 4;
    #pragma unroll
    for (int mg = 0; mg < 2; ++mg)
        #pragma unroll
        for (int ng = 0; ng < 2; ++ng)
            #pragma unroll
            for (int i = 0; i < 4; ++i) {
                const int r = row0 + wm * 32 + mg * 16 + lb * 4 + i;
                const int c = col0 + wn * 32 + ng * 16 + lr;
                out[(size_t)r * DM_ + c] = acc[mg][ng][i];
            }
}

// ---------------------------------------------------------------------------
extern "C" void kernel_launch(void* const* d_in, const int* in_sizes, int n_in,
                              void* d_out, int out_size, void* d_ws, size_t ws_size,
                              hipStream_t stream) {
    const float* x      = (const float*)d_in[0];
    const float* logits = (const float*)d_in[1];
    float* out = (float*)d_out;

    char* p = (char*)d_ws;
    int* sel = (int*)p;                       p += 256;
    const size_t FB = (size_t)B_ * N_ * DM_ * 4;       // 4 MB
    float* Q = (float*)p; p += FB;
    float* K = (float*)p; p += FB;
    float* V = (float*)p; p += FB;
    float* O = (float*)p; p += FB;
    const size_t HB = (size_t)B_ * N_ * DM_ * 2;       // 2 MB
    ush* xh = (ush*)p; p += HB;
    ush* xl = (ush*)p; p += HB;
    const size_t WQ = (size_t)3 * DM_ * DM_ * 2;       // 6 MB (D=1 worst case)
    ush* wqh = (ush*)p; p += WQ;
    ush* wql = (ush*)p; p += WQ;
    const size_t FH = (size_t)DM_ * DM_ * 2;           // 2 MB
    ush* Fh  = (ush*)p; p += FH;
    ush* Fl  = (ush*)p; p += FH;
    ush* woh = (ush*)p; p += FH;
    ush* wol = (ush*)p; p += FH;

    k_select<<<1, 64, 0, stream>>>(logits, sel);

    k_prep_x<<<dim3(B_ * N_ * DM_ / 256), dim3(256), 0, stream>>>(
        sel, x, (const float*)d_in[2], (const float*)d_in[7],
        (const float*)d_in[12], (const float*)d_in[17], xh, xl);
    k_prep_w<<<dim3(3 * DM_ * DM_ / 256), dim3(256), 0, stream>>>(
        sel, (const float*)d_in[3], (const float*)d_in[8],
        (const float*)d_in[13], (const float*)d_in[18], wqh, wql);
    k_qkv<<<dim3(768), dim3(256), 0, stream>>>(sel, xh, xl, wqh, wql, Q, K, V);
    k_attn<<<dim3(16 * 8 * H_ * B_), dim3(256), 0, stream>>>(sel, Q, K, V, O);
    k_mix<<<dim3(B_ * N_ * DM_ / 256), dim3(256), 0, stream>>>(
        sel,
        (const float*)d_in[5],  (const float*)d_in[6],
        (const float*)d_in[10], (const float*)d_in[11],
        (const float*)d_in[15], (const float*)d_in[16],
        (const float*)d_in[20], (const float*)d_in[21],
        O, Fh, Fl);
    k_prep_wo<<<dim3(DM_ * DM_ / 256), dim3(256), 0, stream>>>(
        sel, (const float*)d_in[4], (const float*)d_in[9],
        (const float*)d_in[14], (const float*)d_in[19], woh, wol);
    k_wo<<<dim3(256), dim3(256), 0, stream>>>(Fh, Fl, woh, wol, out);
}

// Round 3
// 140.017 us; speedup vs baseline: 3.8106x; 2.9800x over previous
//
#include <hip/hip_runtime.h>

#define B_   2
#define N_   512
#define DM_  1024
#define H_   16
#define LAM_ 0.1f

typedef __attribute__((ext_vector_type(8))) short bf16x8;
typedef __attribute__((ext_vector_type(4))) float f32x4;
typedef unsigned short ush;

__device__ inline ush f2bf(float v) {
    union { float f; unsigned u; } c; c.f = v;
    unsigned r = c.u + 0x7FFF + ((c.u >> 16) & 1);
    return (ush)(r >> 16);
}
__device__ inline float bf2f(ush b) {
    union { float f; unsigned u; } c; c.u = ((unsigned)b) << 16; return c.f;
}
__device__ inline f32x4 mfma16(bf16x8 a, bf16x8 b, f32x4 c) {
    return __builtin_amdgcn_mfma_f32_16x16x32_bf16(a, b, c, 0, 0, 0);
}

// ---------------------------------------------------------------------------
__global__ void k_select(const float* __restrict__ logits, int* __restrict__ sel) {
    if (threadIdx.x == 0) {
        float best = logits[0]; int bi = 0;
        for (int i = 1; i < 4; ++i) { float v = logits[i]; if (v > best) { best = v; bi = i; } }
        *sel = bi;
    }
}

// ---------------------------------------------------------------------------
// prep: xs = x + pe -> bf16 hi/lo
// ---------------------------------------------------------------------------
__global__ __launch_bounds__(256) void k_prep_x(
        const int* __restrict__ sel, const float* __restrict__ x,
        const float* __restrict__ pe0, const float* __restrict__ pe1,
        const float* __restrict__ pe2, const float* __restrict__ pe3,
        ush* __restrict__ xh, ush* __restrict__ xl) {
    const int s = *sel;
    const float* pe = (s == 0) ? pe0 : (s == 1) ? pe1 : (s == 2) ? pe2 : pe3;
    const size_t i = (size_t)blockIdx.x * 256 + threadIdx.x;
    const float v = x[i] + pe[i % ((size_t)N_ * DM_)];
    const ush h = f2bf(v);
    xh[i] = h; xl[i] = f2bf(v - bf2f(h));
}

// ---------------------------------------------------------------------------
// prep: wqkv [D, ds, 3ds] -> transposed bf16 hi/lo  wt[d][e][s]
// ---------------------------------------------------------------------------
template<int D>
__device__ void prep_w_body(size_t i, const float* __restrict__ w,
                            ush* __restrict__ wh, ush* __restrict__ wl) {
    constexpr int ds = DM_ / D;
    constexpr size_t TOT = (size_t)D * ds * 3 * ds;
    if (i >= TOT) return;
    const int per = ds * 3 * ds;
    const int d = (int)(i / per), rem = (int)(i % per);
    const int s = rem / (3 * ds), e = rem % (3 * ds);
    const float v = w[i];
    const size_t o = (size_t)d * 3 * ds * ds + (size_t)e * ds + s;
    const ush h = f2bf(v);
    wh[o] = h; wl[o] = f2bf(v - bf2f(h));
}
__global__ __launch_bounds__(256) void k_prep_w(
        const int* __restrict__ sel,
        const float* __restrict__ w0, const float* __restrict__ w1,
        const float* __restrict__ w2, const float* __restrict__ w3,
        ush* __restrict__ wh, ush* __restrict__ wl) {
    const size_t i = (size_t)blockIdx.x * 256 + threadIdx.x;
    switch (*sel) {
        case 0: prep_w_body<1>(i, w0, wh, wl); break;
        case 1: prep_w_body<2>(i, w1, wh, wl); break;
        case 2: prep_w_body<4>(i, w2, wh, wl); break;
        case 3: prep_w_body<8>(i, w3, wh, wl); break;
    }
}

// ---------------------------------------------------------------------------
// prep: wo [DM, DM] -> transposed bf16 hi/lo
// ---------------------------------------------------------------------------
__global__ __launch_bounds__(256) void k_prep_wo(
        const int* __restrict__ sel,
        const float* __restrict__ w0, const float* __restrict__ w1,
        const float* __restrict__ w2, const float* __restrict__ w3,
        ush* __restrict__ wh, ush* __restrict__ wl) {
    const int s = *sel;
    const float* w = (s == 0) ? w0 : (s == 1) ? w1 : (s == 2) ? w2 : w3;
    const size_t i = (size_t)blockIdx.x * 256 + threadIdx.x;
    const int k = (int)(i / DM_), j = (int)(i % DM_);
    const float v = w[i];
    const size_t o = (size_t)j * DM_ + k;
    const ush h = f2bf(v);
    wh[o] = h; wl[o] = f2bf(v - bf2f(h));
}

// ---------------------------------------------------------------------------
// Split-bf16 MFMA GEMM core (64x64 tile, BK=32, 4 waves)
// ---------------------------------------------------------------------------
template<int KD>
__device__ void gemm_core(const ush* __restrict__ Ah, const ush* __restrict__ Al, int lda,
                          const ush* __restrict__ Bh, const ush* __restrict__ Bl, int ldb,
                          int row0, int col0, int tid, ush* lds, f32x4 acc[2][2]) {
    ush* lAh = lds; ush* lAl = lds + 2560; ush* lBh = lds + 5120; ush* lBl = lds + 7680;
    const int srow = tid >> 2, scg = tid & 3;
    const int lane = tid & 63, w = tid >> 6;
    const int wm = w >> 1, wn = w & 1;
    const int lr = lane & 15, lb = lane >> 4;

    for (int k0 = 0; k0 < KD; k0 += 32) {
        *(bf16x8*)&lAh[srow * 40 + scg * 8] =
            *(const bf16x8*)&Ah[(size_t)(row0 + srow) * lda + k0 + scg * 8];
        *(bf16x8*)&lAl[srow * 40 + scg * 8] =
            *(const bf16x8*)&Al[(size_t)(row0 + srow) * lda + k0 + scg * 8];
        *(bf16x8*)&lBh[srow * 40 + scg * 8] =
            *(const bf16x8*)&Bh[(size_t)(col0 + srow) * ldb + k0 + scg * 8];
        *(bf16x8*)&lBl[srow * 40 + scg * 8] =
            *(const bf16x8*)&Bl[(size_t)(col0 + srow) * ldb + k0 + scg * 8];
        __syncthreads();
        bf16x8 ah[2], al[2], bh[2], bl[2];
        #pragma unroll
        for (int mg = 0; mg < 2; ++mg) {
            const int r = wm * 32 + mg * 16 + lr;
            ah[mg] = *(const bf16x8*)&lAh[r * 40 + lb * 8];
            al[mg] = *(const bf16x8*)&lAl[r * 40 + lb * 8];
        }
        #pragma unroll
        for (int ng = 0; ng < 2; ++ng) {
            const int r = wn * 32 + ng * 16 + lr;
            bh[ng] = *(const bf16x8*)&lBh[r * 40 + lb * 8];
            bl[ng] = *(const bf16x8*)&lBl[r * 40 + lb * 8];
        }
        #pragma unroll
        for (int mg = 0; mg < 2; ++mg)
            #pragma unroll
            for (int ng = 0; ng < 2; ++ng) {
                acc[mg][ng] = mfma16(ah[mg], bh[ng], acc[mg][ng]);
                acc[mg][ng] = mfma16(al[mg], bh[ng], acc[mg][ng]);
                acc[mg][ng] = mfma16(ah[mg], bl[ng], acc[mg][ng]);
            }
        __syncthreads();
    }
}

// ---------------------------------------------------------------------------
// qkv GEMM; epilogue writes Q,K as bf16 hi/lo [head][n][hd], V as f32
// ---------------------------------------------------------------------------
template<int D>
__device__ void qkv_body(int bid, int tid,
                         const ush* __restrict__ xh, const ush* __restrict__ xl,
                         const ush* __restrict__ wh, const ush* __restrict__ wl,
                         ush* __restrict__ Qh, ush* __restrict__ Ql,
                         ush* __restrict__ Kh, ush* __restrict__ Kl,
                         float* __restrict__ Vf, ush* lds) {
    constexpr int ds = DM_ / D;
    constexpr int hd = ds / H_;
    constexpr int nx = 3 * ds / 64;
    const int bx = bid % nx, by = (bid / nx) & 7, bz = bid / (nx * 8);
    const int b = bz / D, d = bz % D;
    const int row0 = by * 64, col0 = bx * 64;

    f32x4 acc[2][2] = {};
    gemm_core<ds>(xh + (size_t)b * N_ * DM_ + d * ds, xl + (size_t)b * N_ * DM_ + d * ds, DM_,
                  wh + (size_t)d * 3 * ds * ds, wl + (size_t)d * 3 * ds * ds, ds,
                  row0, col0, tid, lds, acc);

    const int lane = tid & 63, w = tid >> 6;
    const int wm = w >> 1, wn = w & 1;
    const int lr = lane & 15, lb = lane >> 4;
    #pragma unroll
    for (int mg = 0; mg < 2; ++mg)
        #pragma unroll
        for (int ng = 0; ng < 2; ++ng)
            #pragma unroll
            for (int i = 0; i < 4; ++i) {
                const int n = row0 + wm * 32 + mg * 16 + lb * 4 + i;
                const int e = col0 + wn * 32 + ng * 16 + lr;
                const int part = e / ds, ep = e % ds;
                const int h = ep / hd, t = ep % hd;
                const size_t head = ((size_t)b * D + d) * H_ + h;
                const size_t o = (head * N_ + n) * hd + t;
                const float v = acc[mg][ng][i];
                if (part == 2) {
                    Vf[o] = v;
                } else {
                    const ush hh = f2bf(v), ll = f2bf(v - bf2f(hh));
                    if (part == 0) { Qh[o] = hh; Ql[o] = ll; }
                    else           { Kh[o] = hh; Kl[o] = ll; }
                }
            }
}
__global__ __launch_bounds__(256) void k_qkv(
        const int* __restrict__ sel,
        const ush* __restrict__ xh, const ush* __restrict__ xl,
        const ush* __restrict__ wh, const ush* __restrict__ wl,
        ush* __restrict__ Qh, ush* __restrict__ Ql,
        ush* __restrict__ Kh, ush* __restrict__ Kl, float* __restrict__ Vf) {
    __shared__ ush lds[4 * 2560];
    const int bid = blockIdx.x, tid = threadIdx.x;
    switch (*sel) {
        case 0: qkv_body<1>(bid, tid, xh, xl, wh, wl, Qh, Ql, Kh, Kl, Vf, lds); break;
        case 1: qkv_body<2>(bid, tid, xh, xl, wh, wl, Qh, Ql, Kh, Kl, Vf, lds); break;
        case 2: qkv_body<4>(bid, tid, xh, xl, wh, wl, Qh, Ql, Kh, Kl, Vf, lds); break;
        case 3: qkv_body<8>(bid, tid, xh, xl, wh, wl, Qh, Ql, Kh, Kl, Vf, lds); break;
    }
}

// ---------------------------------------------------------------------------
// V transpose: [head][n][hd] f32 -> [head][hd][n] bf16 hi/lo (LDS-tiled)
// ---------------------------------------------------------------------------
template<int D>
__device__ void vt_body(int bid, int tid, const float* __restrict__ Vf,
                        ush* __restrict__ Vth, ush* __restrict__ Vtl, float* lds) {
    constexpr int ds = DM_ / D, hd = ds / H_;
    constexpr int NBL = B_ * D * H_ * (N_ / 64);
    if (bid >= NBL) return;
    const int head = bid >> 3, nt = bid & 7;
    const int n0 = nt * 64;
    const size_t hb = (size_t)head * N_ * hd;
    constexpr int LD = hd + 1;
    #pragma unroll
    for (int c = 0; c < hd / 4; ++c) {
        const int lin = c * 256 + tid;
        const int r = lin / hd, cl = lin % hd;
        lds[r * LD + cl] = Vf[hb + (size_t)(n0 + r) * hd + cl];
    }
    __syncthreads();
    #pragma unroll
    for (int c = 0; c < hd / 4; ++c) {
        const int lin = c * 256 + tid;
        const int t = lin >> 6, nn = lin & 63;
        const float v = lds[nn * LD + t];
        const ush hh = f2bf(v);
        Vth[hb + (size_t)t * N_ + n0 + nn] = hh;
        Vtl[hb + (size_t)t * N_ + n0 + nn] = f2bf(v - bf2f(hh));
    }
}
__global__ __launch_bounds__(256) void k_vt(
        const int* __restrict__ sel, const float* __restrict__ Vf,
        ush* __restrict__ Vth, ush* __restrict__ Vtl) {
    __shared__ float lds[64 * 65];
    const int bid = blockIdx.x, tid = threadIdx.x;
    switch (*sel) {
        case 0: vt_body<1>(bid, tid, Vf, Vth, Vtl, lds); break;
        case 1: vt_body<2>(bid, tid, Vf, Vth, Vtl, lds); break;
        case 2: vt_body<4>(bid, tid, Vf, Vth, Vtl, lds); break;
        case 3: vt_body<8>(bid, tid, Vf, Vth, Vtl, lds); break;
    }
}

// ---------------------------------------------------------------------------
// MFMA attention: block = (head, 32 q-rows); 4 waves = 2 q-subtiles x 2 kj-halves
// P staged in LDS bf16 hi/lo with XOR swizzle (G4); K/V fragments from global.
// ---------------------------------------------------------------------------
__device__ inline void p_write(ush* base, int row, int col, ush v) {
    int off = (row << 10) + (col << 1);
    off ^= (row & 7) << 4;
    *(ush*)((char*)base + off) = v;
}
__device__ inline bf16x8 p_read(const ush* base, int row, int col) {
    int off = (row << 10) + (col << 1);
    off ^= (row & 7) << 4;
    return *(const bf16x8*)((const char*)base + off);
}

template<int D>
__device__ void attn_body(int bid, int tid,
        const ush* __restrict__ Qh, const ush* __restrict__ Ql,
        const ush* __restrict__ Kh, const ush* __restrict__ Kl,
        const ush* __restrict__ Vth, const ush* __restrict__ Vtl,
        float* __restrict__ O, ush* P, float* redm, float* redl, float* l_all) {
    constexpr int ds = DM_ / D, hd = ds / H_;
    constexpr int CH = (hd >= 64) ? 2 : 1;
    constexpr int NT = (hd >= 16) ? hd / 16 : 1;
    constexpr int NHEAD = B_ * D * H_;
    if (bid >= 16 * NHEAD) return;
    const int qt = bid & 15, head = bid >> 4;
    const int h = head % H_, d = (head / H_) % D, b = head / (H_ * D);
    const int q0 = qt * 32;
    const size_t hb = (size_t)head * N_ * hd;
    const int lane = tid & 63, w = tid >> 6, wq = w >> 1, wk = w & 1;
    const int lr = lane & 15, lb = lane >> 4;
    const float scale = rsqrtf((float)hd);
    const float RB = LAM_ * (2.0f / N_);
    const bf16x8 z8 = {0, 0, 0, 0, 0, 0, 0, 0};

    // Q A-fragments (natural layout; zero-pad k >= hd in-register)
    bf16x8 qah[CH], qal[CH];
    #pragma unroll
    for (int c = 0; c < CH; ++c) {
        const int k0 = c * 32 + lb * 8;
        bf16x8 vh = z8, vl = z8;
        if (k0 < hd) {
            const size_t o = hb + (size_t)(q0 + wq * 16 + lr) * hd + k0;
            vh = *(const bf16x8*)&Qh[o];
            vl = *(const bf16x8*)&Ql[o];
        }
        qah[c] = vh; qal[c] = vl;
    }

    // S = Q K^T (split-bf16), full row-half in registers
    f32x4 s[16];
    #pragma unroll
    for (int t = 0; t < 16; ++t) {
        const int kj0 = wk * 256 + t * 16;
        f32x4 acc = {0.f, 0.f, 0.f, 0.f};
        #pragma unroll
        for (int c = 0; c < CH; ++c) {
            const int k0 = c * 32 + lb * 8;
            bf16x8 kh8 = z8, kl8 = z8;
            if (k0 < hd) {
                const size_t o = hb + (size_t)(kj0 + lr) * hd + k0;
                kh8 = *(const bf16x8*)&Kh[o];
                kl8 = *(const bf16x8*)&Kl[o];
            }
            acc = mfma16(qah[c], kh8, acc);
            acc = mfma16(qal[c], kh8, acc);
            acc = mfma16(qah[c], kl8, acc);
        }
        s[t] = acc;
    }

    // ring bias + per-wave row max
    float m4[4] = {-1e30f, -1e30f, -1e30f, -1e30f};
    #pragma unroll
    for (int t = 0; t < 16; ++t) {
        const int col = wk * 256 + t * 16 + lr;
        #pragma unroll
        for (int i = 0; i < 4; ++i) {
            const int rn = q0 + wq * 16 + lb * 4 + i;
            int dd = rn - col; dd = dd < 0 ? -dd : dd;
            const int ring = (dd < N_ - dd) ? dd : (N_ - dd);
            const float v = s[t][i] * scale - RB * (float)ring;
            s[t][i] = v;
            m4[i] = fmaxf(m4[i], v);
        }
    }
    #pragma unroll
    for (int i = 0; i < 4; ++i) {
        m4[i] = fmaxf(m4[i], __shfl_xor(m4[i], 1));
        m4[i] = fmaxf(m4[i], __shfl_xor(m4[i], 2));
        m4[i] = fmaxf(m4[i], __shfl_xor(m4[i], 4));
        m4[i] = fmaxf(m4[i], __shfl_xor(m4[i], 8));
    }
    if (lr == 0) {
        #pragma unroll
        for (int i = 0; i < 4; ++i) redm[(wq * 2 + wk) * 16 + lb * 4 + i] = m4[i];
    }
    __syncthreads();
    float mf[4], ls[4] = {0.f, 0.f, 0.f, 0.f};
    #pragma unroll
    for (int i = 0; i < 4; ++i)
        mf[i] = fmaxf(redm[(wq * 2) * 16 + lb * 4 + i], redm[(wq * 2 + 1) * 16 + lb * 4 + i]);

    // exp, P -> LDS (bf16 hi/lo, swizzled), row sums
    ush* Ph = P;
    ush* Pl = P + 32 * 512;
    #pragma unroll
    for (int t = 0; t < 16; ++t) {
        const int col = wk * 256 + t * 16 + lr;
        #pragma unroll
        for (int i = 0; i < 4; ++i) {
            const int row = wq * 16 + lb * 4 + i;
            const float p = __expf(s[t][i] - mf[i]);
            ls[i] += p;
            const ush hh = f2bf(p);
            p_write(Ph, row, col, hh);
            p_write(Pl, row, col, f2bf(p - bf2f(hh)));
        }
    }
    #pragma unroll
    for (int i = 0; i < 4; ++i) {
        ls[i] += __shfl_xor(ls[i], 1);
        ls[i] += __shfl_xor(ls[i], 2);
        ls[i] += __shfl_xor(ls[i], 4);
        ls[i] += __shfl_xor(ls[i], 8);
    }
    if (lr == 0) {
        #pragma unroll
        for (int i = 0; i < 4; ++i) redl[(wq * 2 + wk) * 16 + lb * 4 + i] = ls[i];
    }
    __syncthreads();
    if (wk == 0 && lr == 0) {
        #pragma unroll
        for (int i = 0; i < 4; ++i)
            l_all[wq * 16 + lb * 4 + i] =
                redl[(wq * 2) * 16 + lb * 4 + i] + redl[(wq * 2 + 1) * 16 + lb * 4 + i];
    }

    // PV: each wave handles its own wk j-half, all t-tiles; split-bf16
    f32x4 acc2[NT] = {};
    #pragma unroll
    for (int jc = 0; jc < 8; ++jc) {
        const int j0 = wk * 256 + jc * 32;
        const int prow = wq * 16 + lr;
        const bf16x8 pah = p_read(Ph, prow, j0 + lb * 8);
        const bf16x8 pal = p_read(Pl, prow, j0 + lb * 8);
        #pragma unroll
        for (int tt = 0; tt < NT; ++tt) {
            const size_t o = hb + (size_t)(tt * 16 + lr) * N_ + j0 + lb * 8;
            const bf16x8 vh8 = *(const bf16x8*)&Vth[o];
            const bf16x8 vl8 = *(const bf16x8*)&Vtl[o];
            acc2[tt] = mfma16(pah, vh8, acc2[tt]);
            acc2[tt] = mfma16(pal, vh8, acc2[tt]);
            acc2[tt] = mfma16(pah, vl8, acc2[tt]);
        }
    }
    __syncthreads();  // all P reads done -> alias P region for reduction
    float* res = (float*)P;
    if (wk == 1) {
        #pragma unroll
        for (int tt = 0; tt < NT; ++tt)
            #pragma unroll
            for (int i = 0; i < 4; ++i)
                res[((wq * NT + tt) * 64 + lane) * 4 + i] = acc2[tt][i];
    }
    __syncthreads();
    if (wk == 0) {
        #pragma unroll
        for (int tt = 0; tt < NT; ++tt)
            #pragma unroll
            for (int i = 0; i < 4; ++i) {
                const float o = acc2[tt][i] + res[((wq * NT + tt) * 64 + lane) * 4 + i];
                const int rn = q0 + wq * 16 + lb * 4 + i;
                const int tc = tt * 16 + lr;
                if (tc < hd) {
                    const float linv = 1.0f / l_all[wq * 16 + lb * 4 + i];
                    O[((size_t)b * N_ + rn) * DM_ + d * ds + h * hd + tc] = o * linv;
                }
            }
    }
}
__global__ __launch_bounds__(256) void k_attn(
        const int* __restrict__ sel,
        const ush* __restrict__ Qh, const ush* __restrict__ Ql,
        const ush* __restrict__ Kh, const ush* __restrict__ Kl,
        const ush* __restrict__ Vth, const ush* __restrict__ Vtl,
        float* __restrict__ O) {
    __shared__ __align__(16) ush P[2 * 32 * 512];
    __shared__ float redm[64], redl[64], l_all[32];
    const int bid = blockIdx.x, tid = threadIdx.x;
    switch (*sel) {
        case 0: attn_body<1>(bid, tid, Qh, Ql, Kh, Kl, Vth, Vtl, O, P, redm, redl, l_all); break;
        case 1: attn_body<2>(bid, tid, Qh, Ql, Kh, Kl, Vth, Vtl, O, P, redm, redl, l_all); break;
        case 2: attn_body<4>(bid, tid, Qh, Ql, Kh, Kl, Vth, Vtl, O, P, redm, redl, l_all); break;
        case 3: attn_body<8>(bid, tid, Qh, Ql, Kh, Kl, Vth, Vtl, O, P, redm, redl, l_all); break;
    }
}

// ---------------------------------------------------------------------------
// depth mix: F = einsum(mix, O) -> bf16 hi/lo
// ---------------------------------------------------------------------------
template<int D>
__device__ void mix_body(int bid, int tid, const float* __restrict__ fu,
                         const float* __restrict__ fv, const float* __restrict__ O,
                         ush* __restrict__ Fh, ush* __restrict__ Fl, float* mixs) {
    constexpr int ds = DM_ / D;
    constexpr int R = (D / 4 > 0) ? (D / 4) : 1;
    if (tid < D * D) {
        const int d = tid / D, f = tid % D;
        float m = 0.f;
        #pragma unroll
        for (int rr = 0; rr < R; ++rr) m += fu[d * R + rr] * fv[rr * D + f];
        mixs[tid] = m;
    }
    __syncthreads();
    const size_t idx = (size_t)bid * 256 + tid;
    const int dm = (int)(idx % DM_);
    const size_t bn = idx / DM_;
    const int d = dm / ds, s0 = dm % ds;
    const float* Ob = O + bn * DM_ + s0;
    float acc = 0.f;
    #pragma unroll
    for (int f = 0; f < D; ++f) acc += mixs[d * D + f] * Ob[(size_t)f * ds];
    const ush hh = f2bf(acc);
    Fh[idx] = hh; Fl[idx] = f2bf(acc - bf2f(hh));
}
__global__ __launch_bounds__(256) void k_mix(
        const int* __restrict__ sel,
        const float* __restrict__ fu0, const float* __restrict__ fv0,
        const float* __restrict__ fu1, const float* __restrict__ fv1,
        const float* __restrict__ fu2, const float* __restrict__ fv2,
        const float* __restrict__ fu3, const float* __restrict__ fv3,
        const float* __restrict__ O, ush* __restrict__ Fh, ush* __restrict__ Fl) {
    __shared__ float mixs[64];
    const int bid = blockIdx.x, tid = threadIdx.x;
    switch (*sel) {
        case 0: mix_body<1>(bid, tid, fu0, fv0, O, Fh, Fl, mixs); break;
        case 1: mix_body<2>(bid, tid, fu1, fv1, O, Fh, Fl, mixs); break;
        case 2: mix_body<4>(bid, tid, fu2, fv2, O, Fh, Fl, mixs); break;
        case 3: mix_body<8>(bid, tid, fu3, fv3, O, Fh, Fl, mixs); break;
    }
}

// ---------------------------------------------------------------------------
// out = F @ wo
// ---------------------------------------------------------------------------
__global__ __launch_bounds__(256) void k_wo(
        const ush* __restrict__ Fh, const ush* __restrict__ Fl,
        const ush* __restrict__ wh, const ush* __restrict__ wl,
        float* __restrict__ out) {
    __shared__ ush lds[4 * 2560];
    const int tid = threadIdx.x;
    const int bx = blockIdx.x % 16, by = blockIdx.x / 16;
    const int row0 = by * 64, col0 = bx * 64;
    f32x4 acc[2][2] = {};
    gemm_core<DM_>(Fh, Fl, DM_, wh, wl, DM_, row0, col0, tid, lds, acc);
    const int lane = tid & 63, w = tid >> 6;
    const int wm = w >> 1, wn = w & 1;
    const int lr = lane & 15, lb = lane >> 4;
    #pragma unroll
    for (int mg = 0; mg < 2; ++mg)
        #pragma unroll
        for (int ng = 0; ng < 2; ++ng)
            #pragma unroll
            for (int i = 0; i < 4; ++i) {
                const int r = row0 + wm * 32 + mg * 16 + lb * 4 + i;
                const int c = col0 + wn * 32 + ng * 16 + lr;
                out[(size_t)r * DM_ + c] = acc[mg][ng][i];
            }
}

// ---------------------------------------------------------------------------
extern "C" void kernel_launch(void* const* d_in, const int* in_sizes, int n_in,
                              void* d_out, int out_size, void* d_ws, size_t ws_size,
                              hipStream_t stream) {
    const float* x      = (const float*)d_in[0];
    const float* logits = (const float*)d_in[1];
    float* out = (float*)d_out;

    char* p = (char*)d_ws;
    int* sel = (int*)p; p += 256;
    const size_t MB = 1024 * 1024;
    ush* Qh = (ush*)p; p += 2 * MB;
    ush* Ql = (ush*)p; p += 2 * MB;
    ush* Kh = (ush*)p; p += 2 * MB;
    ush* Kl = (ush*)p; p += 2 * MB;
    float* Vf = (float*)p; p += 4 * MB;
    ush* Vth = (ush*)p; p += 2 * MB + 65536;   // pad for hd=8 garbage-col reads
    ush* Vtl = (ush*)p; p += 2 * MB + 65536;
    float* O = (float*)p; p += 4 * MB;
    ush* xh = (ush*)p; p += 2 * MB;
    ush* xl = (ush*)p; p += 2 * MB;
    ush* wqh = (ush*)p; p += 6 * MB;
    ush* wql = (ush*)p; p += 6 * MB;
    // aliases (consumers of the originals have already run when these are written)
    ush* Fh = xh, *Fl = xl;          // k_mix writes after k_qkv consumed xh/xl
    ush* woh = wqh, *wol = wql;      // k_prep_wo writes after k_qkv consumed wqh/wql

    k_select<<<1, 64, 0, stream>>>(logits, sel);

    k_prep_x<<<dim3(B_ * N_ * DM_ / 256), dim3(256), 0, stream>>>(
        sel, x, (const float*)d_in[2], (const float*)d_in[7],
        (const float*)d_in[12], (const float*)d_in[17], xh, xl);
    k_prep_w<<<dim3(3 * DM_ * DM_ / 256), dim3(256), 0, stream>>>(
        sel, (const float*)d_in[3], (const float*)d_in[8],
        (const float*)d_in[13], (const float*)d_in[18], wqh, wql);
    k_qkv<<<dim3(768), dim3(256), 0, stream>>>(sel, xh, xl, wqh, wql,
                                               Qh, Ql, Kh, Kl, Vf);
    k_vt<<<dim3(2048), dim3(256), 0, stream>>>(sel, Vf, Vth, Vtl);
    k_attn<<<dim3(4096), dim3(256), 0, stream>>>(sel, Qh, Ql, Kh, Kl, Vth, Vtl, O);
    k_mix<<<dim3(B_ * N_ * DM_ / 256), dim3(256), 0, stream>>>(
        sel,
        (const float*)d_in[5],  (const float*)d_in[6],
        (const float*)d_in[10], (const float*)d_in[11],
        (const float*)d_in[15], (const float*)d_in[16],
        (const float*)d_in[20], (const float*)d_in[21],
        O, Fh, Fl);
    k_prep_wo<<<dim3(DM_ * DM_ / 256), dim3(256), 0, stream>>>(
        sel, (const float*)d_in[4], (const float*)d_in[9],
        (const float*)d_in[14], (const float*)d_in[19], woh, wol);
    k_wo<<<dim3(256), dim3(256), 0, stream>>>(Fh, Fl, woh, wol, out);
}

// Round 4
// 119.428 us; speedup vs baseline: 4.4676x; 1.1724x over previous
//
#include <hip/hip_runtime.h>

#define B_   2
#define N_   512
#define DM_  1024
#define H_   16
#define LAM_ 0.1f

typedef __attribute__((ext_vector_type(8))) short bf16x8;
typedef __attribute__((ext_vector_type(4))) float f32x4;
typedef unsigned short ush;

__device__ inline ush f2bf(float v) {
    union { float f; unsigned u; } c; c.f = v;
    unsigned r = c.u + 0x7FFF + ((c.u >> 16) & 1);
    return (ush)(r >> 16);
}
__device__ inline float bf2f(ush b) {
    union { float f; unsigned u; } c; c.u = ((unsigned)b) << 16; return c.f;
}
__device__ inline f32x4 mfma16(bf16x8 a, bf16x8 b, f32x4 c) {
    return __builtin_amdgcn_mfma_f32_16x16x32_bf16(a, b, c, 0, 0, 0);
}

// ---------------------------------------------------------------------------
__global__ void k_select(const float* __restrict__ logits, int* __restrict__ sel) {
    if (threadIdx.x == 0) {
        float best = logits[0]; int bi = 0;
        for (int i = 1; i < 4; ++i) { float v = logits[i]; if (v > best) { best = v; bi = i; } }
        *sel = bi;
    }
}

// ---------------------------------------------------------------------------
// prep: xs = x + pe -> bf16 hi/lo
// ---------------------------------------------------------------------------
__global__ __launch_bounds__(256) void k_prep_x(
        const int* __restrict__ sel, const float* __restrict__ x,
        const float* __restrict__ pe0, const float* __restrict__ pe1,
        const float* __restrict__ pe2, const float* __restrict__ pe3,
        ush* __restrict__ xh, ush* __restrict__ xl) {
    const int s = *sel;
    const float* pe = (s == 0) ? pe0 : (s == 1) ? pe1 : (s == 2) ? pe2 : pe3;
    const size_t i = (size_t)blockIdx.x * 256 + threadIdx.x;
    const float v = x[i] + pe[i % ((size_t)N_ * DM_)];
    const ush h = f2bf(v);
    xh[i] = h; xl[i] = f2bf(v - bf2f(h));
}

// ---------------------------------------------------------------------------
// prep: wqkv [D, ds, 3ds] -> transposed bf16 hi/lo  wt[d][e][s]
// ---------------------------------------------------------------------------
template<int D>
__device__ void prep_w_body(size_t i, const float* __restrict__ w,
                            ush* __restrict__ wh, ush* __restrict__ wl) {
    constexpr int ds = DM_ / D;
    constexpr size_t TOT = (size_t)D * ds * 3 * ds;
    if (i >= TOT) return;
    const int per = ds * 3 * ds;
    const int d = (int)(i / per), rem = (int)(i % per);
    const int s = rem / (3 * ds), e = rem % (3 * ds);
    const float v = w[i];
    const size_t o = (size_t)d * 3 * ds * ds + (size_t)e * ds + s;
    const ush h = f2bf(v);
    wh[o] = h; wl[o] = f2bf(v - bf2f(h));
}
__global__ __launch_bounds__(256) void k_prep_w(
        const int* __restrict__ sel,
        const float* __restrict__ w0, const float* __restrict__ w1,
        const float* __restrict__ w2, const float* __restrict__ w3,
        ush* __restrict__ wh, ush* __restrict__ wl) {
    const size_t i = (size_t)blockIdx.x * 256 + threadIdx.x;
    switch (*sel) {
        case 0: prep_w_body<1>(i, w0, wh, wl); break;
        case 1: prep_w_body<2>(i, w1, wh, wl); break;
        case 2: prep_w_body<4>(i, w2, wh, wl); break;
        case 3: prep_w_body<8>(i, w3, wh, wl); break;
    }
}

// ---------------------------------------------------------------------------
// prep: wo [DM, DM] -> transposed bf16 hi/lo
// ---------------------------------------------------------------------------
__global__ __launch_bounds__(256) void k_prep_wo(
        const int* __restrict__ sel,
        const float* __restrict__ w0, const float* __restrict__ w1,
        const float* __restrict__ w2, const float* __restrict__ w3,
        ush* __restrict__ wh, ush* __restrict__ wl) {
    const int s = *sel;
    const float* w = (s == 0) ? w0 : (s == 1) ? w1 : (s == 2) ? w2 : w3;
    const size_t i = (size_t)blockIdx.x * 256 + threadIdx.x;
    const int k = (int)(i / DM_), j = (int)(i % DM_);
    const float v = w[i];
    const size_t o = (size_t)j * DM_ + k;
    const ush h = f2bf(v);
    wh[o] = h; wl[o] = f2bf(v - bf2f(h));
}

// ---------------------------------------------------------------------------
// Split-bf16 MFMA GEMM core (64x64 tile, BK=32, 4 waves)
// ---------------------------------------------------------------------------
template<int KD>
__device__ void gemm_core(const ush* __restrict__ Ah, const ush* __restrict__ Al, int lda,
                          const ush* __restrict__ Bh, const ush* __restrict__ Bl, int ldb,
                          int row0, int col0, int tid, ush* lds, f32x4 acc[2][2]) {
    ush* lAh = lds; ush* lAl = lds + 2560; ush* lBh = lds + 5120; ush* lBl = lds + 7680;
    const int srow = tid >> 2, scg = tid & 3;
    const int lane = tid & 63, w = tid >> 6;
    const int wm = w >> 1, wn = w & 1;
    const int lr = lane & 15, lb = lane >> 4;

    for (int k0 = 0; k0 < KD; k0 += 32) {
        *(bf16x8*)&lAh[srow * 40 + scg * 8] =
            *(const bf16x8*)&Ah[(size_t)(row0 + srow) * lda + k0 + scg * 8];
        *(bf16x8*)&lAl[srow * 40 + scg * 8] =
            *(const bf16x8*)&Al[(size_t)(row0 + srow) * lda + k0 + scg * 8];
        *(bf16x8*)&lBh[srow * 40 + scg * 8] =
            *(const bf16x8*)&Bh[(size_t)(col0 + srow) * ldb + k0 + scg * 8];
        *(bf16x8*)&lBl[srow * 40 + scg * 8] =
            *(const bf16x8*)&Bl[(size_t)(col0 + srow) * ldb + k0 + scg * 8];
        __syncthreads();
        bf16x8 ah[2], al[2], bh[2], bl[2];
        #pragma unroll
        for (int mg = 0; mg < 2; ++mg) {
            const int r = wm * 32 + mg * 16 + lr;
            ah[mg] = *(const bf16x8*)&lAh[r * 40 + lb * 8];
            al[mg] = *(const bf16x8*)&lAl[r * 40 + lb * 8];
        }
        #pragma unroll
        for (int ng = 0; ng < 2; ++ng) {
            const int r = wn * 32 + ng * 16 + lr;
            bh[ng] = *(const bf16x8*)&lBh[r * 40 + lb * 8];
            bl[ng] = *(const bf16x8*)&lBl[r * 40 + lb * 8];
        }
        #pragma unroll
        for (int mg = 0; mg < 2; ++mg)
            #pragma unroll
            for (int ng = 0; ng < 2; ++ng) {
                acc[mg][ng] = mfma16(ah[mg], bh[ng], acc[mg][ng]);
                acc[mg][ng] = mfma16(al[mg], bh[ng], acc[mg][ng]);
                acc[mg][ng] = mfma16(ah[mg], bl[ng], acc[mg][ng]);
            }
        __syncthreads();
    }
}

// ---------------------------------------------------------------------------
// qkv GEMM; epilogue writes Q,K as bf16 hi/lo [head][n][hd], V as f32
// ---------------------------------------------------------------------------
template<int D>
__device__ void qkv_body(int bid, int tid,
                         const ush* __restrict__ xh, const ush* __restrict__ xl,
                         const ush* __restrict__ wh, const ush* __restrict__ wl,
                         ush* __restrict__ Qh, ush* __restrict__ Ql,
                         ush* __restrict__ Kh, ush* __restrict__ Kl,
                         float* __restrict__ Vf, ush* lds) {
    constexpr int ds = DM_ / D;
    constexpr int hd = ds / H_;
    constexpr int nx = 3 * ds / 64;
    const int bx = bid % nx, by = (bid / nx) & 7, bz = bid / (nx * 8);
    const int b = bz / D, d = bz % D;
    const int row0 = by * 64, col0 = bx * 64;

    f32x4 acc[2][2] = {};
    gemm_core<ds>(xh + (size_t)b * N_ * DM_ + d * ds, xl + (size_t)b * N_ * DM_ + d * ds, DM_,
                  wh + (size_t)d * 3 * ds * ds, wl + (size_t)d * 3 * ds * ds, ds,
                  row0, col0, tid, lds, acc);

    const int lane = tid & 63, w = tid >> 6;
    const int wm = w >> 1, wn = w & 1;
    const int lr = lane & 15, lb = lane >> 4;
    #pragma unroll
    for (int mg = 0; mg < 2; ++mg)
        #pragma unroll
        for (int ng = 0; ng < 2; ++ng)
            #pragma unroll
            for (int i = 0; i < 4; ++i) {
                const int n = row0 + wm * 32 + mg * 16 + lb * 4 + i;
                const int e = col0 + wn * 32 + ng * 16 + lr;
                const int part = e / ds, ep = e % ds;
                const int h = ep / hd, t = ep % hd;
                const size_t head = ((size_t)b * D + d) * H_ + h;
                const size_t o = (head * N_ + n) * hd + t;
                const float v = acc[mg][ng][i];
                if (part == 2) {
                    Vf[o] = v;
                } else {
                    const ush hh = f2bf(v), ll = f2bf(v - bf2f(hh));
                    if (part == 0) { Qh[o] = hh; Ql[o] = ll; }
                    else           { Kh[o] = hh; Kl[o] = ll; }
                }
            }
}
__global__ __launch_bounds__(256) void k_qkv(
        const int* __restrict__ sel,
        const ush* __restrict__ xh, const ush* __restrict__ xl,
        const ush* __restrict__ wh, const ush* __restrict__ wl,
        ush* __restrict__ Qh, ush* __restrict__ Ql,
        ush* __restrict__ Kh, ush* __restrict__ Kl, float* __restrict__ Vf) {
    __shared__ ush lds[4 * 2560];
    const int bid = blockIdx.x, tid = threadIdx.x;
    switch (*sel) {
        case 0: qkv_body<1>(bid, tid, xh, xl, wh, wl, Qh, Ql, Kh, Kl, Vf, lds); break;
        case 1: qkv_body<2>(bid, tid, xh, xl, wh, wl, Qh, Ql, Kh, Kl, Vf, lds); break;
        case 2: qkv_body<4>(bid, tid, xh, xl, wh, wl, Qh, Ql, Kh, Kl, Vf, lds); break;
        case 3: qkv_body<8>(bid, tid, xh, xl, wh, wl, Qh, Ql, Kh, Kl, Vf, lds); break;
    }
}

// ---------------------------------------------------------------------------
// V transpose: [head][n][hd] f32 -> [head][hd][n] bf16 hi/lo (LDS-tiled)
// ---------------------------------------------------------------------------
template<int D>
__device__ void vt_body(int bid, int tid, const float* __restrict__ Vf,
                        ush* __restrict__ Vth, ush* __restrict__ Vtl, float* lds) {
    constexpr int ds = DM_ / D, hd = ds / H_;
    constexpr int NBL = B_ * D * H_ * (N_ / 64);
    if (bid >= NBL) return;
    const int head = bid >> 3, nt = bid & 7;
    const int n0 = nt * 64;
    const size_t hb = (size_t)head * N_ * hd;
    constexpr int LD = hd + 1;
    #pragma unroll
    for (int c = 0; c < hd / 4; ++c) {
        const int lin = c * 256 + tid;
        const int r = lin / hd, cl = lin % hd;
        lds[r * LD + cl] = Vf[hb + (size_t)(n0 + r) * hd + cl];
    }
    __syncthreads();
    #pragma unroll
    for (int c = 0; c < hd / 4; ++c) {
        const int lin = c * 256 + tid;
        const int t = lin >> 6, nn = lin & 63;
        const float v = lds[nn * LD + t];
        const ush hh = f2bf(v);
        Vth[hb + (size_t)t * N_ + n0 + nn] = hh;
        Vtl[hb + (size_t)t * N_ + n0 + nn] = f2bf(v - bf2f(hh));
    }
}
__global__ __launch_bounds__(256) void k_vt(
        const int* __restrict__ sel, const float* __restrict__ Vf,
        ush* __restrict__ Vth, ush* __restrict__ Vtl) {
    __shared__ float lds[64 * 65];
    const int bid = blockIdx.x, tid = threadIdx.x;
    switch (*sel) {
        case 0: vt_body<1>(bid, tid, Vf, Vth, Vtl, lds); break;
        case 1: vt_body<2>(bid, tid, Vf, Vth, Vtl, lds); break;
        case 2: vt_body<4>(bid, tid, Vf, Vth, Vtl, lds); break;
        case 3: vt_body<8>(bid, tid, Vf, Vth, Vtl, lds); break;
    }
}

// ---------------------------------------------------------------------------
// MFMA attention v2: block = (head, 16 q-rows); 4 waves, each owns 128 k-cols.
// P bf16-hi only (denominator accumulated from rounded P for consistency).
// Per-wave P chunk in LDS (swizzled); cross-wave max/sum/res via small LDS.
// XCD-chunked block remap: all q-tiles of a head land on one XCD.
// ---------------------------------------------------------------------------
template<int D>
__device__ void attn_body(int bid, int tid,
        const ush* __restrict__ Qh, const ush* __restrict__ Ql,
        const ush* __restrict__ Kh, const ush* __restrict__ Kl,
        const ush* __restrict__ Vth, const ush* __restrict__ Vtl,
        float* __restrict__ O, ush* P, float* res, float* redm, float* redl) {
    constexpr int ds = DM_ / D, hd = ds / H_;
    constexpr int CH = (hd >= 64) ? 2 : 1;
    constexpr int NT = (hd >= 16) ? hd / 16 : 1;
    constexpr int NHEAD = B_ * D * H_;
    constexpr int NB = NHEAD * 32;
    if (bid >= NB) return;
    // chunked XCD remap: consecutive bidr (same head) share an XCD L2
    const int bidr = (bid & 7) * (NB / 8) + (bid >> 3);
    const int head = bidr >> 5, qt = bidr & 31;
    const int h = head % H_, d = (head / H_) % D, b = head / (H_ * D);
    const int q0 = qt * 16;
    const size_t hb = (size_t)head * N_ * hd;
    const int lane = tid & 63, wk = tid >> 6;   // wave = k-col chunk
    const int lr = lane & 15, lb = lane >> 4;
    const float scale = rsqrtf((float)hd);
    const float RB = LAM_ * (2.0f / N_);
    const bf16x8 z8 = {0, 0, 0, 0, 0, 0, 0, 0};

    // Q A-fragments (row = q0 + lr)
    bf16x8 qah[CH], qal[CH];
    #pragma unroll
    for (int c = 0; c < CH; ++c) {
        const int k0 = c * 32 + lb * 8;
        bf16x8 vh = z8, vl = z8;
        if (k0 < hd) {
            const size_t o = hb + (size_t)(q0 + lr) * hd + k0;
            vh = *(const bf16x8*)&Qh[o];
            vl = *(const bf16x8*)&Ql[o];
        }
        qah[c] = vh; qal[c] = vl;
    }

    // S = Q K^T over this wave's 128 cols (8 tiles), split-bf16
    f32x4 s[8];
    #pragma unroll
    for (int t = 0; t < 8; ++t) {
        const int kj0 = wk * 128 + t * 16;
        f32x4 acc = {0.f, 0.f, 0.f, 0.f};
        #pragma unroll
        for (int c = 0; c < CH; ++c) {
            const int k0 = c * 32 + lb * 8;
            bf16x8 kh8 = z8, kl8 = z8;
            if (k0 < hd) {
                const size_t o = hb + (size_t)(kj0 + lr) * hd + k0;
                kh8 = *(const bf16x8*)&Kh[o];
                kl8 = *(const bf16x8*)&Kl[o];
            }
            acc = mfma16(qah[c], kh8, acc);
            acc = mfma16(qal[c], kh8, acc);
            acc = mfma16(qah[c], kl8, acc);
        }
        s[t] = acc;
    }

    // ring bias + per-wave row max (rows = lb*4+i, cols = lr per tile)
    float m4[4] = {-1e30f, -1e30f, -1e30f, -1e30f};
    #pragma unroll
    for (int t = 0; t < 8; ++t) {
        const int col = wk * 128 + t * 16 + lr;
        #pragma unroll
        for (int i = 0; i < 4; ++i) {
            const int rn = q0 + lb * 4 + i;
            int dd = rn - col; dd = dd < 0 ? -dd : dd;
            const int ring = (dd < N_ - dd) ? dd : (N_ - dd);
            const float v = s[t][i] * scale - RB * (float)ring;
            s[t][i] = v;
            m4[i] = fmaxf(m4[i], v);
        }
    }
    #pragma unroll
    for (int i = 0; i < 4; ++i) {
        m4[i] = fmaxf(m4[i], __shfl_xor(m4[i], 1));
        m4[i] = fmaxf(m4[i], __shfl_xor(m4[i], 2));
        m4[i] = fmaxf(m4[i], __shfl_xor(m4[i], 4));
        m4[i] = fmaxf(m4[i], __shfl_xor(m4[i], 8));
    }
    if (lr == 0) {
        #pragma unroll
        for (int i = 0; i < 4; ++i) redm[wk * 16 + lb * 4 + i] = m4[i];
    }
    __syncthreads();
    float mf[4];
    #pragma unroll
    for (int i = 0; i < 4; ++i) {
        const int r = lb * 4 + i;
        mf[i] = fmaxf(fmaxf(redm[r], redm[16 + r]), fmaxf(redm[32 + r], redm[48 + r]));
    }

    // exp -> bf16 P (hi only); l accumulated from ROUNDED values (consistency)
    ush* Pw = P + wk * 16 * 128;  // per-wave region [16 rows][128 cols]
    float ls[4] = {0.f, 0.f, 0.f, 0.f};
    #pragma unroll
    for (int t = 0; t < 8; ++t) {
        #pragma unroll
        for (int i = 0; i < 4; ++i) {
            const int row = lb * 4 + i;
            const float p = __expf(s[t][i] - mf[i]);
            const ush ph = f2bf(p);
            ls[i] += bf2f(ph);
            int off = (row << 8) + ((t * 16 + lr) << 1);
            off ^= (row & 7) << 4;
            *(ush*)((char*)Pw + off) = ph;
        }
    }
    #pragma unroll
    for (int i = 0; i < 4; ++i) {
        ls[i] += __shfl_xor(ls[i], 1);
        ls[i] += __shfl_xor(ls[i], 2);
        ls[i] += __shfl_xor(ls[i], 4);
        ls[i] += __shfl_xor(ls[i], 8);
    }
    if (lr == 0) {
        #pragma unroll
        for (int i = 0; i < 4; ++i) redl[wk * 16 + lb * 4 + i] = ls[i];
    }

    // PV over this wave's 128 cols (wave-private P region: no barrier needed)
    f32x4 acc2[NT];
    #pragma unroll
    for (int tt = 0; tt < NT; ++tt) acc2[tt] = (f32x4){0.f, 0.f, 0.f, 0.f};
    #pragma unroll
    for (int jc = 0; jc < 4; ++jc) {
        int poff = (lr << 8) + ((jc * 32 + lb * 8) << 1);
        poff ^= (lr & 7) << 4;
        const bf16x8 pa = *(const bf16x8*)((const char*)Pw + poff);
        #pragma unroll
        for (int tt = 0; tt < NT; ++tt) {
            const size_t o = hb + (size_t)(tt * 16 + lr) * N_ + wk * 128 + jc * 32 + lb * 8;
            const bf16x8 vh8 = *(const bf16x8*)&Vth[o];
            const bf16x8 vl8 = *(const bf16x8*)&Vtl[o];
            acc2[tt] = mfma16(pa, vh8, acc2[tt]);
            acc2[tt] = mfma16(pa, vl8, acc2[tt]);
        }
    }
    __syncthreads();
    if (wk != 0) {
        #pragma unroll
        for (int tt = 0; tt < NT; ++tt)
            #pragma unroll
            for (int i = 0; i < 4; ++i)
                res[((wk - 1) * NT + tt) * 256 + i * 64 + lane] = acc2[tt][i];
    }
    __syncthreads();
    if (wk == 0) {
        #pragma unroll
        for (int tt = 0; tt < NT; ++tt)
            #pragma unroll
            for (int i = 0; i < 4; ++i) {
                const float o = acc2[tt][i]
                    + res[(0 * NT + tt) * 256 + i * 64 + lane]
                    + res[(1 * NT + tt) * 256 + i * 64 + lane]
                    + res[(2 * NT + tt) * 256 + i * 64 + lane];
                const int r = lb * 4 + i;
                const int rn = q0 + r;
                const int tc = tt * 16 + lr;
                if (tc < hd) {
                    const float l = redl[r] + redl[16 + r] + redl[32 + r] + redl[48 + r];
                    O[((size_t)b * N_ + rn) * DM_ + d * ds + h * hd + tc] = o / l;
                }
            }
    }
}
__global__ __launch_bounds__(256) void k_attn(
        const int* __restrict__ sel,
        const ush* __restrict__ Qh, const ush* __restrict__ Ql,
        const ush* __restrict__ Kh, const ush* __restrict__ Kl,
        const ush* __restrict__ Vth, const ush* __restrict__ Vtl,
        float* __restrict__ O) {
    __shared__ __align__(16) ush P[4 * 16 * 128];   // 16 KB
    __shared__ float res[3 * 4 * 256];              // 12 KB (NT<=4)
    __shared__ float redm[64], redl[64];
    const int bid = blockIdx.x, tid = threadIdx.x;
    switch (*sel) {
        case 0: attn_body<1>(bid, tid, Qh, Ql, Kh, Kl, Vth, Vtl, O, P, res, redm, redl); break;
        case 1: attn_body<2>(bid, tid, Qh, Ql, Kh, Kl, Vth, Vtl, O, P, res, redm, redl); break;
        case 2: attn_body<4>(bid, tid, Qh, Ql, Kh, Kl, Vth, Vtl, O, P, res, redm, redl); break;
        case 3: attn_body<8>(bid, tid, Qh, Ql, Kh, Kl, Vth, Vtl, O, P, res, redm, redl); break;
    }
}

// ---------------------------------------------------------------------------
// depth mix: F = einsum(mix, O) -> bf16 hi/lo
// ---------------------------------------------------------------------------
template<int D>
__device__ void mix_body(int bid, int tid, const float* __restrict__ fu,
                         const float* __restrict__ fv, const float* __restrict__ O,
                         ush* __restrict__ Fh, ush* __restrict__ Fl, float* mixs) {
    constexpr int ds = DM_ / D;
    constexpr int R = (D / 4 > 0) ? (D / 4) : 1;
    if (tid < D * D) {
        const int d = tid / D, f = tid % D;
        float m = 0.f;
        #pragma unroll
        for (int rr = 0; rr < R; ++rr) m += fu[d * R + rr] * fv[rr * D + f];
        mixs[tid] = m;
    }
    __syncthreads();
    const size_t idx = (size_t)bid * 256 + tid;
    const int dm = (int)(idx % DM_);
    const size_t bn = idx / DM_;
    const int d = dm / ds, s0 = dm % ds;
    const float* Ob = O + bn * DM_ + s0;
    float acc = 0.f;
    #pragma unroll
    for (int f = 0; f < D; ++f) acc += mixs[d * D + f] * Ob[(size_t)f * ds];
    const ush hh = f2bf(acc);
    Fh[idx] = hh; Fl[idx] = f2bf(acc - bf2f(hh));
}
__global__ __launch_bounds__(256) void k_mix(
        const int* __restrict__ sel,
        const float* __restrict__ fu0, const float* __restrict__ fv0,
        const float* __restrict__ fu1, const float* __restrict__ fv1,
        const float* __restrict__ fu2, const float* __restrict__ fv2,
        const float* __restrict__ fu3, const float* __restrict__ fv3,
        const float* __restrict__ O, ush* __restrict__ Fh, ush* __restrict__ Fl) {
    __shared__ float mixs[64];
    const int bid = blockIdx.x, tid = threadIdx.x;
    switch (*sel) {
        case 0: mix_body<1>(bid, tid, fu0, fv0, O, Fh, Fl, mixs); break;
        case 1: mix_body<2>(bid, tid, fu1, fv1, O, Fh, Fl, mixs); break;
        case 2: mix_body<4>(bid, tid, fu2, fv2, O, Fh, Fl, mixs); break;
        case 3: mix_body<8>(bid, tid, fu3, fv3, O, Fh, Fl, mixs); break;
    }
}

// ---------------------------------------------------------------------------
// out = F @ wo
// ---------------------------------------------------------------------------
__global__ __launch_bounds__(256) void k_wo(
        const ush* __restrict__ Fh, const ush* __restrict__ Fl,
        const ush* __restrict__ wh, const ush* __restrict__ wl,
        float* __restrict__ out) {
    __shared__ ush lds[4 * 2560];
    const int tid = threadIdx.x;
    const int bx = blockIdx.x % 16, by = blockIdx.x / 16;
    const int row0 = by * 64, col0 = bx * 64;
    f32x4 acc[2][2] = {};
    gemm_core<DM_>(Fh, Fl, DM_, wh, wl, DM_, row0, col0, tid, lds, acc);
    const int lane = tid & 63, w = tid >> 6;
    const int wm = w >> 1, wn = w & 1;
    const int lr = lane & 15, lb = lane >> 4;
    #pragma unroll
    for (int mg = 0; mg < 2; ++mg)
        #pragma unroll
        for (int ng = 0; ng < 2; ++ng)
            #pragma unroll
            for (int i = 0; i < 4; ++i) {
                const int r = row0 + wm * 32 + mg * 16 + lb * 4 + i;
                const int c = col0 + wn * 32 + ng * 16 + lr;
                out[(size_t)r * DM_ + c] = acc[mg][ng][i];
            }
}

// ---------------------------------------------------------------------------
extern "C" void kernel_launch(void* const* d_in, const int* in_sizes, int n_in,
                              void* d_out, int out_size, void* d_ws, size_t ws_size,
                              hipStream_t stream) {
    const float* x      = (const float*)d_in[0];
    const float* logits = (const float*)d_in[1];
    float* out = (float*)d_out;

    char* p = (char*)d_ws;
    int* sel = (int*)p; p += 256;
    const size_t MB = 1024 * 1024;
    ush* Qh = (ush*)p; p += 2 * MB;
    ush* Ql = (ush*)p; p += 2 * MB;
    ush* Kh = (ush*)p; p += 2 * MB;
    ush* Kl = (ush*)p; p += 2 * MB;
    float* Vf = (float*)p; p += 4 * MB;
    ush* Vth = (ush*)p; p += 2 * MB + 65536;   // pad for hd=8 garbage-row reads
    ush* Vtl = (ush*)p; p += 2 * MB + 65536;
    float* O = (float*)p; p += 4 * MB;
    ush* xh = (ush*)p; p += 2 * MB;
    ush* xl = (ush*)p; p += 2 * MB;
    ush* wqh = (ush*)p; p += 6 * MB;
    ush* wql = (ush*)p; p += 6 * MB;
    // aliases (originals fully consumed before these are written)
    ush* Fh = xh, *Fl = xl;
    ush* woh = wqh, *wol = wql;

    k_select<<<1, 64, 0, stream>>>(logits, sel);

    k_prep_x<<<dim3(B_ * N_ * DM_ / 256), dim3(256), 0, stream>>>(
        sel, x, (const float*)d_in[2], (const float*)d_in[7],
        (const float*)d_in[12], (const float*)d_in[17], xh, xl);
    k_prep_w<<<dim3(3 * DM_ * DM_ / 256), dim3(256), 0, stream>>>(
        sel, (const float*)d_in[3], (const float*)d_in[8],
        (const float*)d_in[13], (const float*)d_in[18], wqh, wql);
    k_qkv<<<dim3(768), dim3(256), 0, stream>>>(sel, xh, xl, wqh, wql,
                                               Qh, Ql, Kh, Kl, Vf);
    k_vt<<<dim3(2048), dim3(256), 0, stream>>>(sel, Vf, Vth, Vtl);
    k_attn<<<dim3(8192), dim3(256), 0, stream>>>(sel, Qh, Ql, Kh, Kl, Vth, Vtl, O);
    k_mix<<<dim3(B_ * N_ * DM_ / 256), dim3(256), 0, stream>>>(
        sel,
        (const float*)d_in[5],  (const float*)d_in[6],
        (const float*)d_in[10], (const float*)d_in[11],
        (const float*)d_in[15], (const float*)d_in[16],
        (const float*)d_in[20], (const float*)d_in[21],
        O, Fh, Fl);
    k_prep_wo<<<dim3(DM_ * DM_ / 256), dim3(256), 0, stream>>>(
        sel, (const float*)d_in[4], (const float*)d_in[9],
        (const float*)d_in[14], (const float*)d_in[19], woh, wol);
    k_wo<<<dim3(256), dim3(256), 0, stream>>>(Fh, Fl, woh, wol, out);
}

// Round 6
// 109.152 us; speedup vs baseline: 4.8882x; 1.0941x over previous
//
#include <hip/hip_runtime.h>

#define B_   2
#define N_   512
#define DM_  1024
#define H_   16
#define LAM_ 0.1f

typedef __attribute__((ext_vector_type(8))) short bf16x8;
typedef __attribute__((ext_vector_type(4))) float f32x4;
typedef unsigned short ush;
struct ush4 { ush x, y, z, w; };

__device__ inline ush f2bf(float v) {
    union { float f; unsigned u; } c; c.f = v;
    unsigned r = c.u + 0x7FFF + ((c.u >> 16) & 1);
    return (ush)(r >> 16);
}
__device__ inline float bf2f(ush b) {
    union { float f; unsigned u; } c; c.u = ((unsigned)b) << 16; return c.f;
}
__device__ inline f32x4 mfma16(bf16x8 a, bf16x8 b, f32x4 c) {
    return __builtin_amdgcn_mfma_f32_16x16x32_bf16(a, b, c, 0, 0, 0);
}

// ---------------------------------------------------------------------------
__global__ void k_select(const float* __restrict__ logits, int* __restrict__ sel) {
    if (threadIdx.x == 0) {
        float best = logits[0]; int bi = 0;
        for (int i = 1; i < 4; ++i) { float v = logits[i]; if (v > best) { best = v; bi = i; } }
        *sel = bi;
    }
}

// ---------------------------------------------------------------------------
// fused prep. Region map (256-thread blocks):
//   [0,     4096): x+pe -> bf16 hi/lo        (B*N*DM/256   = 4096)
//   [4096, 16384): wqkv transpose            (3*DM*DM/256  = 12288)
//   [16384,20480): wo transpose              (DM*DM/256    = 4096)
// ---------------------------------------------------------------------------
template<int D>
__device__ void prep_w_body(size_t i, const float* __restrict__ w,
                            ush* __restrict__ wh, ush* __restrict__ wl) {
    constexpr int ds = DM_ / D;
    constexpr size_t TOT = (size_t)D * ds * 3 * ds;
    if (i >= TOT) return;
    const int per = ds * 3 * ds;
    const int d = (int)(i / per), rem = (int)(i % per);
    const int s = rem / (3 * ds), e = rem % (3 * ds);
    const float v = w[i];
    const size_t o = (size_t)d * 3 * ds * ds + (size_t)e * ds + s;
    const ush h = f2bf(v);
    wh[o] = h; wl[o] = f2bf(v - bf2f(h));
}
__global__ __launch_bounds__(256) void k_prep(
        const int* __restrict__ sel, const float* __restrict__ x,
        const float* __restrict__ pe0, const float* __restrict__ pe1,
        const float* __restrict__ pe2, const float* __restrict__ pe3,
        const float* __restrict__ w0, const float* __restrict__ w1,
        const float* __restrict__ w2, const float* __restrict__ w3,
        const float* __restrict__ wo0, const float* __restrict__ wo1,
        const float* __restrict__ wo2, const float* __restrict__ wo3,
        ush* __restrict__ xh, ush* __restrict__ xl,
        ush* __restrict__ wqh, ush* __restrict__ wql,
        ush* __restrict__ woh, ush* __restrict__ wol) {
    const int s = *sel;
    const int bid = blockIdx.x, tid = threadIdx.x;
    if (bid < 4096) {                        // x + pe  (i < B*N*DM = 1,048,576)
        const float* pe = (s == 0) ? pe0 : (s == 1) ? pe1 : (s == 2) ? pe2 : pe3;
        const size_t i = (size_t)bid * 256 + tid;
        const float v = x[i] + pe[i % ((size_t)N_ * DM_)];
        const ush h = f2bf(v);
        xh[i] = h; xl[i] = f2bf(v - bf2f(h));
    } else if (bid < 16384) {                // wqkv transpose (i < 3*DM*DM)
        const size_t i = (size_t)(bid - 4096) * 256 + tid;
        switch (s) {
            case 0: prep_w_body<1>(i, w0, wqh, wql); break;
            case 1: prep_w_body<2>(i, w1, wqh, wql); break;
            case 2: prep_w_body<4>(i, w2, wqh, wql); break;
            case 3: prep_w_body<8>(i, w3, wqh, wql); break;
        }
    } else {                                 // wo transpose (i < DM*DM)
        const float* w = (s == 0) ? wo0 : (s == 1) ? wo1 : (s == 2) ? wo2 : wo3;
        const size_t i = (size_t)(bid - 16384) * 256 + tid;
        const int k = (int)(i / DM_), j = (int)(i % DM_);
        const float v = w[i];
        const size_t o = (size_t)j * DM_ + k;
        const ush h = f2bf(v);
        woh[o] = h; wol[o] = f2bf(v - bf2f(h));
    }
}

// ---------------------------------------------------------------------------
// Split-bf16 MFMA GEMM core (64x64 tile, BK=32, 4 waves)
// ---------------------------------------------------------------------------
template<int KD>
__device__ void gemm_core(const ush* __restrict__ Ah, const ush* __restrict__ Al, int lda,
                          const ush* __restrict__ Bh, const ush* __restrict__ Bl, int ldb,
                          int row0, int col0, int tid, ush* lds, f32x4 acc[2][2]) {
    ush* lAh = lds; ush* lAl = lds + 2560; ush* lBh = lds + 5120; ush* lBl = lds + 7680;
    const int srow = tid >> 2, scg = tid & 3;
    const int lane = tid & 63, w = tid >> 6;
    const int wm = w >> 1, wn = w & 1;
    const int lr = lane & 15, lb = lane >> 4;

    for (int k0 = 0; k0 < KD; k0 += 32) {
        *(bf16x8*)&lAh[srow * 40 + scg * 8] =
            *(const bf16x8*)&Ah[(size_t)(row0 + srow) * lda + k0 + scg * 8];
        *(bf16x8*)&lAl[srow * 40 + scg * 8] =
            *(const bf16x8*)&Al[(size_t)(row0 + srow) * lda + k0 + scg * 8];
        *(bf16x8*)&lBh[srow * 40 + scg * 8] =
            *(const bf16x8*)&Bh[(size_t)(col0 + srow) * ldb + k0 + scg * 8];
        *(bf16x8*)&lBl[srow * 40 + scg * 8] =
            *(const bf16x8*)&Bl[(size_t)(col0 + srow) * ldb + k0 + scg * 8];
        __syncthreads();
        bf16x8 ah[2], al[2], bh[2], bl[2];
        #pragma unroll
        for (int mg = 0; mg < 2; ++mg) {
            const int r = wm * 32 + mg * 16 + lr;
            ah[mg] = *(const bf16x8*)&lAh[r * 40 + lb * 8];
            al[mg] = *(const bf16x8*)&lAl[r * 40 + lb * 8];
        }
        #pragma unroll
        for (int ng = 0; ng < 2; ++ng) {
            const int r = wn * 32 + ng * 16 + lr;
            bh[ng] = *(const bf16x8*)&lBh[r * 40 + lb * 8];
            bl[ng] = *(const bf16x8*)&lBl[r * 40 + lb * 8];
        }
        #pragma unroll
        for (int mg = 0; mg < 2; ++mg)
            #pragma unroll
            for (int ng = 0; ng < 2; ++ng) {
                acc[mg][ng] = mfma16(ah[mg], bh[ng], acc[mg][ng]);
                acc[mg][ng] = mfma16(al[mg], bh[ng], acc[mg][ng]);
                acc[mg][ng] = mfma16(ah[mg], bl[ng], acc[mg][ng]);
            }
        __syncthreads();
    }
}

// ---------------------------------------------------------------------------
// qkv GEMM; epilogue: Q,K bf16 hi/lo [head][n][hd]; V written TRANSPOSED
// bf16 hi/lo [head][t][n] via packed 8B stores (i-consecutive rows)
// ---------------------------------------------------------------------------
template<int D>
__device__ void qkv_body(int bid, int tid,
                         const ush* __restrict__ xh, const ush* __restrict__ xl,
                         const ush* __restrict__ wh, const ush* __restrict__ wl,
                         ush* __restrict__ Qh, ush* __restrict__ Ql,
                         ush* __restrict__ Kh, ush* __restrict__ Kl,
                         ush* __restrict__ Vth, ush* __restrict__ Vtl, ush* lds) {
    constexpr int ds = DM_ / D;
    constexpr int hd = ds / H_;
    constexpr int nx = 3 * ds / 64;
    const int bx = bid % nx, by = (bid / nx) & 7, bz = bid / (nx * 8);
    const int b = bz / D, d = bz % D;
    const int row0 = by * 64, col0 = bx * 64;

    f32x4 acc[2][2] = {};
    gemm_core<ds>(xh + (size_t)b * N_ * DM_ + d * ds, xl + (size_t)b * N_ * DM_ + d * ds, DM_,
                  wh + (size_t)d * 3 * ds * ds, wl + (size_t)d * 3 * ds * ds, ds,
                  row0, col0, tid, lds, acc);

    const int lane = tid & 63, w = tid >> 6;
    const int wm = w >> 1, wn = w & 1;
    const int lr = lane & 15, lb = lane >> 4;
    #pragma unroll
    for (int mg = 0; mg < 2; ++mg)
        #pragma unroll
        for (int ng = 0; ng < 2; ++ng) {
            const int n0 = row0 + wm * 32 + mg * 16 + lb * 4;
            const int e  = col0 + wn * 32 + ng * 16 + lr;
            const int part = e / ds, ep = e % ds;
            const int h = ep / hd, t = ep % hd;
            const size_t head = ((size_t)b * D + d) * H_ + h;
            if (part == 2) {
                ush4 h4, l4;
                const float v0 = acc[mg][ng][0], v1 = acc[mg][ng][1];
                const float v2 = acc[mg][ng][2], v3 = acc[mg][ng][3];
                h4.x = f2bf(v0); l4.x = f2bf(v0 - bf2f(h4.x));
                h4.y = f2bf(v1); l4.y = f2bf(v1 - bf2f(h4.y));
                h4.z = f2bf(v2); l4.z = f2bf(v2 - bf2f(h4.z));
                h4.w = f2bf(v3); l4.w = f2bf(v3 - bf2f(h4.w));
                const size_t o = (head * hd + t) * N_ + n0;
                *(ush4*)&Vth[o] = h4;
                *(ush4*)&Vtl[o] = l4;
            } else {
                #pragma unroll
                for (int i = 0; i < 4; ++i) {
                    const size_t o = (head * N_ + n0 + i) * hd + t;
                    const float v = acc[mg][ng][i];
                    const ush hh = f2bf(v), ll = f2bf(v - bf2f(hh));
                    if (part == 0) { Qh[o] = hh; Ql[o] = ll; }
                    else           { Kh[o] = hh; Kl[o] = ll; }
                }
            }
        }
}
__global__ __launch_bounds__(256) void k_qkv(
        const int* __restrict__ sel,
        const ush* __restrict__ xh, const ush* __restrict__ xl,
        const ush* __restrict__ wh, const ush* __restrict__ wl,
        ush* __restrict__ Qh, ush* __restrict__ Ql,
        ush* __restrict__ Kh, ush* __restrict__ Kl,
        ush* __restrict__ Vth, ush* __restrict__ Vtl) {
    __shared__ ush lds[4 * 2560];
    const int bid = blockIdx.x, tid = threadIdx.x;
    switch (*sel) {
        case 0: qkv_body<1>(bid, tid, xh, xl, wh, wl, Qh, Ql, Kh, Kl, Vth, Vtl, lds); break;
        case 1: qkv_body<2>(bid, tid, xh, xl, wh, wl, Qh, Ql, Kh, Kl, Vth, Vtl, lds); break;
        case 2: qkv_body<4>(bid, tid, xh, xl, wh, wl, Qh, Ql, Kh, Kl, Vth, Vtl, lds); break;
        case 3: qkv_body<8>(bid, tid, xh, xl, wh, wl, Qh, Ql, Kh, Kl, Vth, Vtl, lds); break;
    }
}

// ---------------------------------------------------------------------------
// MFMA attention v3: block = (head, 16 q-rows); 4 waves x 128 k-cols.
// Per-wave max (log2 domain), no barriers until final combine; paired
// v_cvt_pk_bf16_f32 for P; res aliased onto P after PV.
// ---------------------------------------------------------------------------
template<int D>
__device__ void attn_body(int bid, int tid,
        const ush* __restrict__ Qh, const ush* __restrict__ Ql,
        const ush* __restrict__ Kh, const ush* __restrict__ Kl,
        const ush* __restrict__ Vth, const ush* __restrict__ Vtl,
        float* __restrict__ O, ush* P, float* redm, float* redl) {
    constexpr int ds = DM_ / D, hd = ds / H_;
    constexpr int CH = (hd >= 64) ? 2 : 1;
    constexpr int NT = (hd >= 16) ? hd / 16 : 1;
    constexpr int NHEAD = B_ * D * H_;
    constexpr int NB = NHEAD * 32;
    if (bid >= NB) return;
    const int bidr = (bid & 7) * (NB / 8) + (bid >> 3);
    const int head = bidr >> 5, qt = bidr & 31;
    const int h = head % H_, d = (head / H_) % D, b = head / (H_ * D);
    const int q0 = qt * 16;
    const size_t hb = (size_t)head * N_ * hd;
    const int lane = tid & 63, wk = tid >> 6;
    const int lr = lane & 15, lb = lane >> 4;
    const float L2E = 1.44269504f;
    const float SC  = rsqrtf((float)hd) * L2E;
    const float RB2 = LAM_ * (2.0f / N_) * L2E;
    const bf16x8 z8 = {0, 0, 0, 0, 0, 0, 0, 0};

    bf16x8 qah[CH], qal[CH];
    #pragma unroll
    for (int c = 0; c < CH; ++c) {
        const int k0 = c * 32 + lb * 8;
        bf16x8 vh = z8, vl = z8;
        if (k0 < hd) {
            const size_t o = hb + (size_t)(q0 + lr) * hd + k0;
            vh = *(const bf16x8*)&Qh[o];
            vl = *(const bf16x8*)&Ql[o];
        }
        qah[c] = vh; qal[c] = vl;
    }

    f32x4 s[8];
    #pragma unroll
    for (int t = 0; t < 8; ++t) {
        const int kj0 = wk * 128 + t * 16;
        f32x4 acc = {0.f, 0.f, 0.f, 0.f};
        #pragma unroll
        for (int c = 0; c < CH; ++c) {
            const int k0 = c * 32 + lb * 8;
            bf16x8 kh8 = z8, kl8 = z8;
            if (k0 < hd) {
                const size_t o = hb + (size_t)(kj0 + lr) * hd + k0;
                kh8 = *(const bf16x8*)&Kh[o];
                kl8 = *(const bf16x8*)&Kl[o];
            }
            acc = mfma16(qah[c], kh8, acc);
            acc = mfma16(qal[c], kh8, acc);
            acc = mfma16(qah[c], kl8, acc);
        }
        s[t] = acc;
    }

    float m4[4] = {-1e30f, -1e30f, -1e30f, -1e30f};
    #pragma unroll
    for (int t = 0; t < 8; ++t) {
        const int col = wk * 128 + t * 16 + lr;
        #pragma unroll
        for (int i = 0; i < 4; ++i) {
            const int rn = q0 + lb * 4 + i;
            int dd = rn - col; dd = dd < 0 ? -dd : dd;
            const int ring = (dd < N_ - dd) ? dd : (N_ - dd);
            const float v = s[t][i] * SC - RB2 * (float)ring;
            s[t][i] = v;
            m4[i] = fmaxf(m4[i], v);
        }
    }
    #pragma unroll
    for (int i = 0; i < 4; ++i) {
        m4[i] = fmaxf(m4[i], __shfl_xor(m4[i], 1));
        m4[i] = fmaxf(m4[i], __shfl_xor(m4[i], 2));
        m4[i] = fmaxf(m4[i], __shfl_xor(m4[i], 4));
        m4[i] = fmaxf(m4[i], __shfl_xor(m4[i], 8));
    }
    if (lr == 0) {
        #pragma unroll
        for (int i = 0; i < 4; ++i) redm[wk * 16 + lb * 4 + i] = m4[i];
    }

    ush* Pw = P + wk * 2048;
    float ls[4] = {0.f, 0.f, 0.f, 0.f};
    #pragma unroll
    for (int t = 0; t < 8; t += 2) {
        #pragma unroll
        for (int i = 0; i < 4; ++i) {
            const int row = lb * 4 + i;
            const float pe = exp2f(s[t][i] - m4[i]);
            const float po = exp2f(s[t + 1][i] - m4[i]);
            unsigned pk;
            asm("v_cvt_pk_bf16_f32 %0, %1, %2" : "=v"(pk) : "v"(pe), "v"(po));
            union { unsigned u; float f; } clo, chi;
            clo.u = pk << 16;
            chi.u = pk & 0xffff0000u;
            ls[i] += clo.f + chi.f;
            const int swz = (row & 7) << 4;
            const int offe = ((row << 8) + ((t * 16 + lr) << 1)) ^ swz;
            const int offo = ((row << 8) + (((t + 1) * 16 + lr) << 1)) ^ swz;
            *(ush*)((char*)Pw + offe) = (ush)pk;
            *(ush*)((char*)Pw + offo) = (ush)(pk >> 16);
        }
    }
    #pragma unroll
    for (int i = 0; i < 4; ++i) {
        ls[i] += __shfl_xor(ls[i], 1);
        ls[i] += __shfl_xor(ls[i], 2);
        ls[i] += __shfl_xor(ls[i], 4);
        ls[i] += __shfl_xor(ls[i], 8);
    }
    if (lr == 0) {
        #pragma unroll
        for (int i = 0; i < 4; ++i) redl[wk * 16 + lb * 4 + i] = ls[i];
    }

    f32x4 acc2[NT];
    #pragma unroll
    for (int tt = 0; tt < NT; ++tt) acc2[tt] = (f32x4){0.f, 0.f, 0.f, 0.f};
    #pragma unroll
    for (int jc = 0; jc < 4; ++jc) {
        int poff = ((lr << 8) + ((jc * 32 + lb * 8) << 1)) ^ ((lr & 7) << 4);
        const bf16x8 pa = *(const bf16x8*)((const char*)Pw + poff);
        #pragma unroll
        for (int tt = 0; tt < NT; ++tt) {
            const size_t o = hb + (size_t)(tt * 16 + lr) * N_ + wk * 128 + jc * 32 + lb * 8;
            const bf16x8 vh8 = *(const bf16x8*)&Vth[o];
            const bf16x8 vl8 = *(const bf16x8*)&Vtl[o];
            acc2[tt] = mfma16(pa, vh8, acc2[tt]);
            acc2[tt] = mfma16(pa, vl8, acc2[tt]);
        }
    }

    __syncthreads();
    float* res = (float*)P;
    if (wk != 0) {
        #pragma unroll
        for (int tt = 0; tt < NT; ++tt)
            #pragma unroll
            for (int i = 0; i < 4; ++i)
                res[((wk - 1) * NT + tt) * 256 + i * 64 + lane] = acc2[tt][i];
    }
    __syncthreads();
    if (wk == 0) {
        float scw[4][4], linv[4];
        #pragma unroll
        for (int i = 0; i < 4; ++i) {
            const int r = lb * 4 + i;
            const float mw0 = redm[r], mw1 = redm[16 + r];
            const float mw2 = redm[32 + r], mw3 = redm[48 + r];
            const float m = fmaxf(fmaxf(mw0, mw1), fmaxf(mw2, mw3));
            scw[i][0] = exp2f(mw0 - m); scw[i][1] = exp2f(mw1 - m);
            scw[i][2] = exp2f(mw2 - m); scw[i][3] = exp2f(mw3 - m);
            const float l = redl[r] * scw[i][0] + redl[16 + r] * scw[i][1]
                          + redl[32 + r] * scw[i][2] + redl[48 + r] * scw[i][3];
            linv[i] = 1.0f / l;
        }
        #pragma unroll
        for (int tt = 0; tt < NT; ++tt)
            #pragma unroll
            for (int i = 0; i < 4; ++i) {
                const float o = acc2[tt][i] * scw[i][0]
                    + res[(0 * NT + tt) * 256 + i * 64 + lane] * scw[i][1]
                    + res[(1 * NT + tt) * 256 + i * 64 + lane] * scw[i][2]
                    + res[(2 * NT + tt) * 256 + i * 64 + lane] * scw[i][3];
                const int rn = q0 + lb * 4 + i;
                const int tc = tt * 16 + lr;
                if (tc < hd)
                    O[((size_t)b * N_ + rn) * DM_ + d * ds + h * hd + tc] = o * linv[i];
            }
    }
}
__global__ __launch_bounds__(256) void k_attn(
        const int* __restrict__ sel,
        const ush* __restrict__ Qh, const ush* __restrict__ Ql,
        const ush* __restrict__ Kh, const ush* __restrict__ Kl,
        const ush* __restrict__ Vth, const ush* __restrict__ Vtl,
        float* __restrict__ O) {
    __shared__ __align__(16) ush P[4 * 16 * 128];   // 16 KB; res aliases this
    __shared__ float redm[64], redl[64];
    const int bid = blockIdx.x, tid = threadIdx.x;
    switch (*sel) {
        case 0: attn_body<1>(bid, tid, Qh, Ql, Kh, Kl, Vth, Vtl, O, P, redm, redl); break;
        case 1: attn_body<2>(bid, tid, Qh, Ql, Kh, Kl, Vth, Vtl, O, P, redm, redl); break;
        case 2: attn_body<4>(bid, tid, Qh, Ql, Kh, Kl, Vth, Vtl, O, P, redm, redl); break;
        case 3: attn_body<8>(bid, tid, Qh, Ql, Kh, Kl, Vth, Vtl, O, P, redm, redl); break;
    }
}

// ---------------------------------------------------------------------------
// depth mix: F = einsum(mix, O) -> bf16 hi/lo
// ---------------------------------------------------------------------------
template<int D>
__device__ void mix_body(int bid, int tid, const float* __restrict__ fu,
                         const float* __restrict__ fv, const float* __restrict__ O,
                         ush* __restrict__ Fh, ush* __restrict__ Fl, float* mixs) {
    constexpr int ds = DM_ / D;
    constexpr int R = (D / 4 > 0) ? (D / 4) : 1;
    if (tid < D * D) {
        const int d = tid / D, f = tid % D;
        float m = 0.f;
        #pragma unroll
        for (int rr = 0; rr < R; ++rr) m += fu[d * R + rr] * fv[rr * D + f];
        mixs[tid] = m;
    }
    __syncthreads();
    const size_t idx = (size_t)bid * 256 + tid;
    const int dm = (int)(idx % DM_);
    const size_t bn = idx / DM_;
    const int d = dm / ds, s0 = dm % ds;
    const float* Ob = O + bn * DM_ + s0;
    float acc = 0.f;
    #pragma unroll
    for (int f = 0; f < D; ++f) acc += mixs[d * D + f] * Ob[(size_t)f * ds];
    const ush hh = f2bf(acc);
    Fh[idx] = hh; Fl[idx] = f2bf(acc - bf2f(hh));
}
__global__ __launch_bounds__(256) void k_mix(
        const int* __restrict__ sel,
        const float* __restrict__ fu0, const float* __restrict__ fv0,
        const float* __restrict__ fu1, const float* __restrict__ fv1,
        const float* __restrict__ fu2, const float* __restrict__ fv2,
        const float* __restrict__ fu3, const float* __restrict__ fv3,
        const float* __restrict__ O, ush* __restrict__ Fh, ush* __restrict__ Fl) {
    __shared__ float mixs[64];
    const int bid = blockIdx.x, tid = threadIdx.x;
    switch (*sel) {
        case 0: mix_body<1>(bid, tid, fu0, fv0, O, Fh, Fl, mixs); break;
        case 1: mix_body<2>(bid, tid, fu1, fv1, O, Fh, Fl, mixs); break;
        case 2: mix_body<4>(bid, tid, fu2, fv2, O, Fh, Fl, mixs); break;
        case 3: mix_body<8>(bid, tid, fu3, fv3, O, Fh, Fl, mixs); break;
    }
}

// ---------------------------------------------------------------------------
// out = F @ wo
// ---------------------------------------------------------------------------
__global__ __launch_bounds__(256) void k_wo(
        const ush* __restrict__ Fh, const ush* __restrict__ Fl,
        const ush* __restrict__ wh, const ush* __restrict__ wl,
        float* __restrict__ out) {
    __shared__ ush lds[4 * 2560];
    const int tid = threadIdx.x;
    const int bx = blockIdx.x % 16, by = blockIdx.x / 16;
    const int row0 = by * 64, col0 = bx * 64;
    f32x4 acc[2][2] = {};
    gemm_core<DM_>(Fh, Fl, DM_, wh, wl, DM_, row0, col0, tid, lds, acc);
    const int lane = tid & 63, w = tid >> 6;
    const int wm = w >> 1, wn = w & 1;
    const int lr = lane & 15, lb = lane >> 4;
    #pragma unroll
    for (int mg = 0; mg < 2; ++mg)
        #pragma unroll
        for (int ng = 0; ng < 2; ++ng)
            #pragma unroll
            for (int i = 0; i < 4; ++i) {
                const int r = row0 + wm * 32 + mg * 16 + lb * 4 + i;
                const int c = col0 + wn * 32 + ng * 16 + lr;
                out[(size_t)r * DM_ + c] = acc[mg][ng][i];
            }
}

// ---------------------------------------------------------------------------
extern "C" void kernel_launch(void* const* d_in, const int* in_sizes, int n_in,
                              void* d_out, int out_size, void* d_ws, size_t ws_size,
                              hipStream_t stream) {
    const float* x      = (const float*)d_in[0];
    const float* logits = (const float*)d_in[1];
    float* out = (float*)d_out;

    char* p = (char*)d_ws;
    int* sel = (int*)p; p += 256;
    const size_t MB = 1024 * 1024;
    ush* Qh = (ush*)p; p += 2 * MB;
    ush* Ql = (ush*)p; p += 2 * MB;
    ush* Kh = (ush*)p; p += 2 * MB;
    ush* Kl = (ush*)p; p += 2 * MB;
    ush* Vth = (ush*)p; p += 2 * MB + 65536;   // pad: hd=8 garbage-row reads
    ush* Vtl = (ush*)p; p += 2 * MB + 65536;
    float* O = (float*)p; p += 4 * MB;
    ush* xh = (ush*)p; p += 2 * MB;
    ush* xl = (ush*)p; p += 2 * MB;
    ush* wqh = (ush*)p; p += 6 * MB;
    ush* wql = (ush*)p; p += 6 * MB;
    ush* woh = (ush*)p; p += 2 * MB;
    ush* wol = (ush*)p; p += 2 * MB;
    ush* Fh = xh, *Fl = xl;   // k_mix writes after k_qkv consumed xh/xl

    k_select<<<1, 64, 0, stream>>>(logits, sel);
    k_prep<<<dim3(20480), dim3(256), 0, stream>>>(
        sel, x,
        (const float*)d_in[2], (const float*)d_in[7],
        (const float*)d_in[12], (const float*)d_in[17],
        (const float*)d_in[3], (const float*)d_in[8],
        (const float*)d_in[13], (const float*)d_in[18],
        (const float*)d_in[4], (const float*)d_in[9],
        (const float*)d_in[14], (const float*)d_in[19],
        xh, xl, wqh, wql, woh, wol);
    k_qkv<<<dim3(768), dim3(256), 0, stream>>>(sel, xh, xl, wqh, wql,
                                               Qh, Ql, Kh, Kl, Vth, Vtl);
    k_attn<<<dim3(8192), dim3(256), 0, stream>>>(sel, Qh, Ql, Kh, Kl, Vth, Vtl, O);
    k_mix<<<dim3(B_ * N_ * DM_ / 256), dim3(256), 0, stream>>>(
        sel,
        (const float*)d_in[5],  (const float*)d_in[6],
        (const float*)d_in[10], (const float*)d_in[11],
        (const float*)d_in[15], (const float*)d_in[16],
        (const float*)d_in[20], (const float*)d_in[21],
        O, Fh, Fl);
    k_wo<<<dim3(256), dim3(256), 0, stream>>>(Fh, Fl, woh, wol, out);
}

// Round 7
// 89.581 us; speedup vs baseline: 5.9561x; 1.2185x over previous
//
#include <hip/hip_runtime.h>

#define B_   2
#define N_   512
#define DM_  1024
#define H_   16
#define LAM_ 0.1f

typedef __attribute__((ext_vector_type(8))) short bf16x8;
typedef __attribute__((ext_vector_type(4))) float f32x4;
typedef unsigned short ush;
struct ush4 { ush x, y, z, w; };
struct uint2s { unsigned x, y; };

__device__ inline ush f2bf(float v) {
    union { float f; unsigned u; } c; c.f = v;
    unsigned r = c.u + 0x7FFF + ((c.u >> 16) & 1);
    return (ush)(r >> 16);
}
__device__ inline float bf2f(ush b) {
    union { float f; unsigned u; } c; c.u = ((unsigned)b) << 16; return c.f;
}
__device__ inline f32x4 mfma16(bf16x8 a, bf16x8 b, f32x4 c) {
    return __builtin_amdgcn_mfma_f32_16x16x32_bf16(a, b, c, 0, 0, 0);
}

// ---------------------------------------------------------------------------
__global__ void k_select(const float* __restrict__ logits, int* __restrict__ sel) {
    if (threadIdx.x == 0) {
        float best = logits[0]; int bi = 0;
        for (int i = 1; i < 4; ++i) { float v = logits[i]; if (v > best) { best = v; bi = i; } }
        *sel = bi;
    }
}

// ---------------------------------------------------------------------------
// fused prep v2 (coalesced transposes via LDS tiles). Region map:
//   [0,    1024): x+pe -> bf16 hi/lo, float4-vectorized
//   [1024, 1792): wqkv transpose, 64x64 LDS tiles (active count varies by D)
//   [1792, 2048): wo transpose, 64x64 LDS tiles
// ---------------------------------------------------------------------------
template<int D>
__device__ void prep_wt_tile(int bT, int tid, const float* __restrict__ w,
                             ush* __restrict__ wh, ush* __restrict__ wl,
                             float (*lds)[65]) {
    constexpr int ds = DM_ / D;
    constexpr int tpr = 3 * ds / 64;          // e-tiles per row
    constexpr int tpc = ds / 64;              // s-tiles
    constexpr int tpd = tpr * tpc;
    if (bT >= D * tpd) return;
    const int d = bT / tpd, rem = bT % tpd;
    const int tr = rem / tpr, tc = rem % tpr; // s-tile, e-tile
    const float* src = w + (size_t)d * ds * 3 * ds;
    ush* dsth = wh + (size_t)d * 3 * ds * ds;
    ush* dstl = wl + (size_t)d * 3 * ds * ds;
    const int c = tid & 63, r0 = tid >> 6;
    #pragma unroll
    for (int j = 0; j < 16; ++j) {
        const int r = j * 4 + r0;
        lds[r][c] = src[(size_t)(tr * 64 + r) * (3 * ds) + tc * 64 + c];
    }
    __syncthreads();
    #pragma unroll
    for (int j = 0; j < 16; ++j) {
        const int r = j * 4 + r0;
        const float v = lds[c][r];
        const size_t o = (size_t)(tc * 64 + r) * ds + tr * 64 + c;
        const ush h = f2bf(v);
        dsth[o] = h; dstl[o] = f2bf(v - bf2f(h));
    }
}
__global__ __launch_bounds__(256) void k_prep(
        const int* __restrict__ sel, const float* __restrict__ x,
        const float* __restrict__ pe0, const float* __restrict__ pe1,
        const float* __restrict__ pe2, const float* __restrict__ pe3,
        const float* __restrict__ w0, const float* __restrict__ w1,
        const float* __restrict__ w2, const float* __restrict__ w3,
        const float* __restrict__ wo0, const float* __restrict__ wo1,
        const float* __restrict__ wo2, const float* __restrict__ wo3,
        ush* __restrict__ xh, ush* __restrict__ xl,
        ush* __restrict__ wqh, ush* __restrict__ wql,
        ush* __restrict__ woh, ush* __restrict__ wol) {
    __shared__ float lds[64][65];
    const int s = *sel;
    const int bid = blockIdx.x, tid = threadIdx.x;
    if (bid < 1024) {                        // x + pe, 4 elems/thread
        const float* pe = (s == 0) ? pe0 : (s == 1) ? pe1 : (s == 2) ? pe2 : pe3;
        const size_t i0 = ((size_t)bid * 256 + tid) * 4;
        const float4 xv = *(const float4*)&x[i0];
        const float4 pv = *(const float4*)&pe[i0 & ((size_t)N_ * DM_ - 1)];
        ush4 h4, l4;
        float v;
        v = xv.x + pv.x; h4.x = f2bf(v); l4.x = f2bf(v - bf2f(h4.x));
        v = xv.y + pv.y; h4.y = f2bf(v); l4.y = f2bf(v - bf2f(h4.y));
        v = xv.z + pv.z; h4.z = f2bf(v); l4.z = f2bf(v - bf2f(h4.z));
        v = xv.w + pv.w; h4.w = f2bf(v); l4.w = f2bf(v - bf2f(h4.w));
        *(ush4*)&xh[i0] = h4;
        *(ush4*)&xl[i0] = l4;
    } else if (bid < 1792) {                 // wqkv transpose
        const int bT = bid - 1024;
        switch (s) {
            case 0: prep_wt_tile<1>(bT, tid, w0, wqh, wql, lds); break;
            case 1: prep_wt_tile<2>(bT, tid, w1, wqh, wql, lds); break;
            case 2: prep_wt_tile<4>(bT, tid, w2, wqh, wql, lds); break;
            case 3: prep_wt_tile<8>(bT, tid, w3, wqh, wql, lds); break;
        }
    } else {                                 // wo transpose
        const float* w = (s == 0) ? wo0 : (s == 1) ? wo1 : (s == 2) ? wo2 : wo3;
        const int bT = bid - 1792;
        const int tr = bT >> 4, tc = bT & 15;
        const int c = tid & 63, r0 = tid >> 6;
        #pragma unroll
        for (int j = 0; j < 16; ++j) {
            const int r = j * 4 + r0;
            lds[r][c] = w[(size_t)(tr * 64 + r) * DM_ + tc * 64 + c];
        }
        __syncthreads();
        #pragma unroll
        for (int j = 0; j < 16; ++j) {
            const int r = j * 4 + r0;
            const float v = lds[c][r];
            const size_t o = (size_t)(tc * 64 + r) * DM_ + tr * 64 + c;
            const ush h = f2bf(v);
            woh[o] = h; wol[o] = f2bf(v - bf2f(h));
        }
    }
}

// ---------------------------------------------------------------------------
// Split-bf16 MFMA GEMM core (64x64 tile, BK=32, 4 waves) — used by k_qkv
// ---------------------------------------------------------------------------
template<int KD>
__device__ void gemm_core(const ush* __restrict__ Ah, const ush* __restrict__ Al, int lda,
                          const ush* __restrict__ Bh, const ush* __restrict__ Bl, int ldb,
                          int row0, int col0, int tid, ush* lds, f32x4 acc[2][2]) {
    ush* lAh = lds; ush* lAl = lds + 2560; ush* lBh = lds + 5120; ush* lBl = lds + 7680;
    const int srow = tid >> 2, scg = tid & 3;
    const int lane = tid & 63, w = tid >> 6;
    const int wm = w >> 1, wn = w & 1;
    const int lr = lane & 15, lb = lane >> 4;

    for (int k0 = 0; k0 < KD; k0 += 32) {
        *(bf16x8*)&lAh[srow * 40 + scg * 8] =
            *(const bf16x8*)&Ah[(size_t)(row0 + srow) * lda + k0 + scg * 8];
        *(bf16x8*)&lAl[srow * 40 + scg * 8] =
            *(const bf16x8*)&Al[(size_t)(row0 + srow) * lda + k0 + scg * 8];
        *(bf16x8*)&lBh[srow * 40 + scg * 8] =
            *(const bf16x8*)&Bh[(size_t)(col0 + srow) * ldb + k0 + scg * 8];
        *(bf16x8*)&lBl[srow * 40 + scg * 8] =
            *(const bf16x8*)&Bl[(size_t)(col0 + srow) * ldb + k0 + scg * 8];
        __syncthreads();
        bf16x8 ah[2], al[2], bh[2], bl[2];
        #pragma unroll
        for (int mg = 0; mg < 2; ++mg) {
            const int r = wm * 32 + mg * 16 + lr;
            ah[mg] = *(const bf16x8*)&lAh[r * 40 + lb * 8];
            al[mg] = *(const bf16x8*)&lAl[r * 40 + lb * 8];
        }
        #pragma unroll
        for (int ng = 0; ng < 2; ++ng) {
            const int r = wn * 32 + ng * 16 + lr;
            bh[ng] = *(const bf16x8*)&lBh[r * 40 + lb * 8];
            bl[ng] = *(const bf16x8*)&lBl[r * 40 + lb * 8];
        }
        #pragma unroll
        for (int mg = 0; mg < 2; ++mg)
            #pragma unroll
            for (int ng = 0; ng < 2; ++ng) {
                acc[mg][ng] = mfma16(ah[mg], bh[ng], acc[mg][ng]);
                acc[mg][ng] = mfma16(al[mg], bh[ng], acc[mg][ng]);
                acc[mg][ng] = mfma16(ah[mg], bl[ng], acc[mg][ng]);
            }
        __syncthreads();
    }
}

// ---------------------------------------------------------------------------
// qkv GEMM; epilogue: Q,K bf16 hi/lo [head][n][hd]; V TRANSPOSED bf16 hi/lo
// ---------------------------------------------------------------------------
template<int D>
__device__ void qkv_body(int bid, int tid,
                         const ush* __restrict__ xh, const ush* __restrict__ xl,
                         const ush* __restrict__ wh, const ush* __restrict__ wl,
                         ush* __restrict__ Qh, ush* __restrict__ Ql,
                         ush* __restrict__ Kh, ush* __restrict__ Kl,
                         ush* __restrict__ Vth, ush* __restrict__ Vtl, ush* lds) {
    constexpr int ds = DM_ / D;
    constexpr int hd = ds / H_;
    constexpr int nx = 3 * ds / 64;
    const int bx = bid % nx, by = (bid / nx) & 7, bz = bid / (nx * 8);
    const int b = bz / D, d = bz % D;
    const int row0 = by * 64, col0 = bx * 64;

    f32x4 acc[2][2] = {};
    gemm_core<ds>(xh + (size_t)b * N_ * DM_ + d * ds, xl + (size_t)b * N_ * DM_ + d * ds, DM_,
                  wh + (size_t)d * 3 * ds * ds, wl + (size_t)d * 3 * ds * ds, ds,
                  row0, col0, tid, lds, acc);

    const int lane = tid & 63, w = tid >> 6;
    const int wm = w >> 1, wn = w & 1;
    const int lr = lane & 15, lb = lane >> 4;
    #pragma unroll
    for (int mg = 0; mg < 2; ++mg)
        #pragma unroll
        for (int ng = 0; ng < 2; ++ng) {
            const int n0 = row0 + wm * 32 + mg * 16 + lb * 4;
            const int e  = col0 + wn * 32 + ng * 16 + lr;
            const int part = e / ds, ep = e % ds;
            const int h = ep / hd, t = ep % hd;
            const size_t head = ((size_t)b * D + d) * H_ + h;
            if (part == 2) {
                ush4 h4, l4;
                const float v0 = acc[mg][ng][0], v1 = acc[mg][ng][1];
                const float v2 = acc[mg][ng][2], v3 = acc[mg][ng][3];
                h4.x = f2bf(v0); l4.x = f2bf(v0 - bf2f(h4.x));
                h4.y = f2bf(v1); l4.y = f2bf(v1 - bf2f(h4.y));
                h4.z = f2bf(v2); l4.z = f2bf(v2 - bf2f(h4.z));
                h4.w = f2bf(v3); l4.w = f2bf(v3 - bf2f(h4.w));
                const size_t o = (head * hd + t) * N_ + n0;
                *(ush4*)&Vth[o] = h4;
                *(ush4*)&Vtl[o] = l4;
            } else {
                #pragma unroll
                for (int i = 0; i < 4; ++i) {
                    const size_t o = (head * N_ + n0 + i) * hd + t;
                    const float v = acc[mg][ng][i];
                    const ush hh = f2bf(v), ll = f2bf(v - bf2f(hh));
                    if (part == 0) { Qh[o] = hh; Ql[o] = ll; }
                    else           { Kh[o] = hh; Kl[o] = ll; }
                }
            }
        }
}
__global__ __launch_bounds__(256) void k_qkv(
        const int* __restrict__ sel,
        const ush* __restrict__ xh, const ush* __restrict__ xl,
        const ush* __restrict__ wh, const ush* __restrict__ wl,
        ush* __restrict__ Qh, ush* __restrict__ Ql,
        ush* __restrict__ Kh, ush* __restrict__ Kl,
        ush* __restrict__ Vth, ush* __restrict__ Vtl) {
    __shared__ ush lds[4 * 2560];
    const int bid = blockIdx.x, tid = threadIdx.x;
    switch (*sel) {
        case 0: qkv_body<1>(bid, tid, xh, xl, wh, wl, Qh, Ql, Kh, Kl, Vth, Vtl, lds); break;
        case 1: qkv_body<2>(bid, tid, xh, xl, wh, wl, Qh, Ql, Kh, Kl, Vth, Vtl, lds); break;
        case 2: qkv_body<4>(bid, tid, xh, xl, wh, wl, Qh, Ql, Kh, Kl, Vth, Vtl, lds); break;
        case 3: qkv_body<8>(bid, tid, xh, xl, wh, wl, Qh, Ql, Kh, Kl, Vth, Vtl, lds); break;
    }
}

// ---------------------------------------------------------------------------
// MFMA attention v4: swapped QK^T (C col = q-row -> lane-local rows),
// NO max subtraction (m=0; power-of-2 rescale exactness makes this safe for
// |s|<~120), packed 8B P stores, l lane-local + 2 shfls. Zero barriers until
// the final cross-wave combine.
// ---------------------------------------------------------------------------
template<int D>
__device__ void attn_body(int bid, int tid,
        const ush* __restrict__ Qh, const ush* __restrict__ Ql,
        const ush* __restrict__ Kh, const ush* __restrict__ Kl,
        const ush* __restrict__ Vth, const ush* __restrict__ Vtl,
        float* __restrict__ O, ush* P, float* redl) {
    constexpr int ds = DM_ / D, hd = ds / H_;
    constexpr int CH = (hd >= 64) ? 2 : 1;
    constexpr int NT = (hd >= 16) ? hd / 16 : 1;
    constexpr int NHEAD = B_ * D * H_;
    constexpr int NB = NHEAD * 32;
    if (bid >= NB) return;
    const int bidr = (bid & 7) * (NB / 8) + (bid >> 3);
    const int head = bidr >> 5, qt = bidr & 31;
    const int h = head % H_, d = (head / H_) % D, b = head / (H_ * D);
    const int q0 = qt * 16;
    const size_t hb = (size_t)head * N_ * hd;
    const int lane = tid & 63, wk = tid >> 6;
    const int lr = lane & 15, lb = lane >> 4;
    const float L2E = 1.44269504f;
    const float SC  = rsqrtf((float)hd) * L2E;
    const float RB2 = LAM_ * (2.0f / N_) * L2E;
    const bf16x8 z8 = {0, 0, 0, 0, 0, 0, 0, 0};

    // Q fragment (B-operand): lane holds q-row q0+lr, k-slice lb*8
    bf16x8 qah[CH], qal[CH];
    #pragma unroll
    for (int c = 0; c < CH; ++c) {
        const int k0 = c * 32 + lb * 8;
        bf16x8 vh = z8, vl = z8;
        if (k0 < hd) {
            const size_t o = hb + (size_t)(q0 + lr) * hd + k0;
            vh = *(const bf16x8*)&Qh[o];
            vl = *(const bf16x8*)&Ql[o];
        }
        qah[c] = vh; qal[c] = vl;
    }

    // S^T = K Q^T: C[row=k(lb*4+i), col=q(lr)] per 16x16 tile
    f32x4 s[8];
    #pragma unroll
    for (int t = 0; t < 8; ++t) {
        const int kj0 = wk * 128 + t * 16;
        f32x4 acc = {0.f, 0.f, 0.f, 0.f};
        #pragma unroll
        for (int c = 0; c < CH; ++c) {
            const int k0 = c * 32 + lb * 8;
            bf16x8 kh8 = z8, kl8 = z8;
            if (k0 < hd) {
                const size_t o = hb + (size_t)(kj0 + lr) * hd + k0;
                kh8 = *(const bf16x8*)&Kh[o];
                kl8 = *(const bf16x8*)&Kl[o];
            }
            acc = mfma16(kh8, qah[c], acc);
            acc = mfma16(kl8, qah[c], acc);
            acc = mfma16(kh8, qal[c], acc);
        }
        s[t] = acc;
    }

    // bias + exp2 + packed bf16 P (8B store per tile) + lane-local row sum
    ush* Pw = P + wk * 2048;   // [16 q-rows][128 k-cols], row stride 256B
    const int q = q0 + lr;
    float ls = 0.f;
    #pragma unroll
    for (int t = 0; t < 8; ++t) {
        const int kbase = wk * 128 + t * 16 + lb * 4;
        float p[4];
        #pragma unroll
        for (int i = 0; i < 4; ++i) {
            int dd = q - (kbase + i); dd = dd < 0 ? -dd : dd;
            const int ring = (dd < N_ - dd) ? dd : (N_ - dd);
            p[i] = exp2f(s[t][i] * SC - RB2 * (float)ring);
        }
        unsigned pk0, pk1;
        asm("v_cvt_pk_bf16_f32 %0, %1, %2" : "=v"(pk0) : "v"(p[0]), "v"(p[1]));
        asm("v_cvt_pk_bf16_f32 %0, %1, %2" : "=v"(pk1) : "v"(p[2]), "v"(p[3]));
        union { unsigned u; float f; } c0, c1, c2, c3;
        c0.u = pk0 << 16; c1.u = pk0 & 0xffff0000u;
        c2.u = pk1 << 16; c3.u = pk1 & 0xffff0000u;
        ls += (c0.f + c1.f) + (c2.f + c3.f);
        const int off = ((lr << 8) + ((t * 16 + lb * 4) << 1)) ^ ((lr & 7) << 4);
        uint2s pv; pv.x = pk0; pv.y = pk1;
        *(uint2s*)((char*)Pw + off) = pv;
    }
    // reduce over the 4 lb-groups that share q-row lr
    ls += __shfl_xor(ls, 16);
    ls += __shfl_xor(ls, 32);
    if (lb == 0) redl[wk * 16 + lr] = ls;

    // PV over this wave's 128 cols (wave-private P region)
    f32x4 acc2[NT];
    #pragma unroll
    for (int tt = 0; tt < NT; ++tt) acc2[tt] = (f32x4){0.f, 0.f, 0.f, 0.f};
    #pragma unroll
    for (int jc = 0; jc < 4; ++jc) {
        int poff = ((lr << 8) + ((jc * 32 + lb * 8) << 1)) ^ ((lr & 7) << 4);
        const bf16x8 pa = *(const bf16x8*)((const char*)Pw + poff);
        #pragma unroll
        for (int tt = 0; tt < NT; ++tt) {
            const size_t o = hb + (size_t)(tt * 16 + lr) * N_ + wk * 128 + jc * 32 + lb * 8;
            const bf16x8 vh8 = *(const bf16x8*)&Vth[o];
            const bf16x8 vl8 = *(const bf16x8*)&Vtl[o];
            acc2[tt] = mfma16(pa, vh8, acc2[tt]);
            acc2[tt] = mfma16(pa, vl8, acc2[tt]);
        }
    }

    __syncthreads();
    float* res = (float*)P;
    if (wk != 0) {
        #pragma unroll
        for (int tt = 0; tt < NT; ++tt)
            #pragma unroll
            for (int i = 0; i < 4; ++i)
                res[((wk - 1) * NT + tt) * 256 + i * 64 + lane] = acc2[tt][i];
    }
    __syncthreads();
    if (wk == 0) {
        float linv[4];
        #pragma unroll
        for (int i = 0; i < 4; ++i) {
            const int r = lb * 4 + i;
            linv[i] = 1.0f / (redl[r] + redl[16 + r] + redl[32 + r] + redl[48 + r]);
        }
        #pragma unroll
        for (int tt = 0; tt < NT; ++tt)
            #pragma unroll
            for (int i = 0; i < 4; ++i) {
                const float o = acc2[tt][i]
                    + res[(0 * NT + tt) * 256 + i * 64 + lane]
                    + res[(1 * NT + tt) * 256 + i * 64 + lane]
                    + res[(2 * NT + tt) * 256 + i * 64 + lane];
                const int rn = q0 + lb * 4 + i;
                const int tc = tt * 16 + lr;
                if (tc < hd)
                    O[((size_t)b * N_ + rn) * DM_ + d * ds + h * hd + tc] = o * linv[i];
            }
    }
}
__global__ __launch_bounds__(256) void k_attn(
        const int* __restrict__ sel,
        const ush* __restrict__ Qh, const ush* __restrict__ Ql,
        const ush* __restrict__ Kh, const ush* __restrict__ Kl,
        const ush* __restrict__ Vth, const ush* __restrict__ Vtl,
        float* __restrict__ O) {
    __shared__ __align__(16) ush P[4 * 16 * 128];   // 16 KB; res aliases this
    __shared__ float redl[64];
    const int bid = blockIdx.x, tid = threadIdx.x;
    switch (*sel) {
        case 0: attn_body<1>(bid, tid, Qh, Ql, Kh, Kl, Vth, Vtl, O, P, redl); break;
        case 1: attn_body<2>(bid, tid, Qh, Ql, Kh, Kl, Vth, Vtl, O, P, redl); break;
        case 2: attn_body<4>(bid, tid, Qh, Ql, Kh, Kl, Vth, Vtl, O, P, redl); break;
        case 3: attn_body<8>(bid, tid, Qh, Ql, Kh, Kl, Vth, Vtl, O, P, redl); break;
    }
}

// ---------------------------------------------------------------------------
// depth mix: F = einsum(mix, O) -> bf16 hi/lo
// ---------------------------------------------------------------------------
template<int D>
__device__ void mix_body(int bid, int tid, const float* __restrict__ fu,
                         const float* __restrict__ fv, const float* __restrict__ O,
                         ush* __restrict__ Fh, ush* __restrict__ Fl, float* mixs) {
    constexpr int ds = DM_ / D;
    constexpr int R = (D / 4 > 0) ? (D / 4) : 1;
    if (tid < D * D) {
        const int d = tid / D, f = tid % D;
        float m = 0.f;
        #pragma unroll
        for (int rr = 0; rr < R; ++rr) m += fu[d * R + rr] * fv[rr * D + f];
        mixs[tid] = m;
    }
    __syncthreads();
    const size_t idx = (size_t)bid * 256 + tid;
    const int dm = (int)(idx % DM_);
    const size_t bn = idx / DM_;
    const int d = dm / ds, s0 = dm % ds;
    const float* Ob = O + bn * DM_ + s0;
    float acc = 0.f;
    #pragma unroll
    for (int f = 0; f < D; ++f) acc += mixs[d * D + f] * Ob[(size_t)f * ds];
    const ush hh = f2bf(acc);
    Fh[idx] = hh; Fl[idx] = f2bf(acc - bf2f(hh));
}
__global__ __launch_bounds__(256) void k_mix(
        const int* __restrict__ sel,
        const float* __restrict__ fu0, const float* __restrict__ fv0,
        const float* __restrict__ fu1, const float* __restrict__ fv1,
        const float* __restrict__ fu2, const float* __restrict__ fv2,
        const float* __restrict__ fu3, const float* __restrict__ fv3,
        const float* __restrict__ O, ush* __restrict__ Fh, ush* __restrict__ Fl) {
    __shared__ float mixs[64];
    const int bid = blockIdx.x, tid = threadIdx.x;
    switch (*sel) {
        case 0: mix_body<1>(bid, tid, fu0, fv0, O, Fh, Fl, mixs); break;
        case 1: mix_body<2>(bid, tid, fu1, fv1, O, Fh, Fl, mixs); break;
        case 2: mix_body<4>(bid, tid, fu2, fv2, O, Fh, Fl, mixs); break;
        case 3: mix_body<8>(bid, tid, fu3, fv3, O, Fh, Fl, mixs); break;
    }
}

// ---------------------------------------------------------------------------
// out = F @ wo — 32x64 tiles, grid 512 (2 blocks/CU for latency hiding)
// 4 waves: wq = row half (16 rows), wn = col half (32 cols)
// ---------------------------------------------------------------------------
__global__ __launch_bounds__(256) void k_wo(
        const ush* __restrict__ Fh, const ush* __restrict__ Fl,
        const ush* __restrict__ wh, const ush* __restrict__ wl,
        float* __restrict__ out) {
    __shared__ ush lA[2][32 * 40];
    __shared__ ush lB[2][64 * 40];
    const int tid = threadIdx.x;
    const int bx = blockIdx.x & 15, by = blockIdx.x >> 4;
    const int row0 = by * 32, col0 = bx * 64;
    const int lane = tid & 63, w = tid >> 6;
    const int wq = w >> 1, wn = w & 1;
    const int lr = lane & 15, lb = lane >> 4;
    f32x4 acc[2] = {};

    for (int k0 = 0; k0 < DM_; k0 += 32) {
        {   // A: threads 0-127 stage hi, 128-255 stage lo
            const int half = tid >> 7, t2 = tid & 127;
            const int srow = t2 >> 2, scg = t2 & 3;
            const ush* src = half ? Fl : Fh;
            *(bf16x8*)&lA[half][srow * 40 + scg * 8] =
                *(const bf16x8*)&src[(size_t)(row0 + srow) * DM_ + k0 + scg * 8];
        }
        {   // B: all 256 threads stage hi then lo
            const int srow = tid >> 2, scg = tid & 3;
            *(bf16x8*)&lB[0][srow * 40 + scg * 8] =
                *(const bf16x8*)&wh[(size_t)(col0 + srow) * DM_ + k0 + scg * 8];
            *(bf16x8*)&lB[1][srow * 40 + scg * 8] =
                *(const bf16x8*)&wl[(size_t)(col0 + srow) * DM_ + k0 + scg * 8];
        }
        __syncthreads();
        const int ar = wq * 16 + lr;
        const bf16x8 ah = *(const bf16x8*)&lA[0][ar * 40 + lb * 8];
        const bf16x8 al = *(const bf16x8*)&lA[1][ar * 40 + lb * 8];
        #pragma unroll
        for (int ng = 0; ng < 2; ++ng) {
            const int br = wn * 32 + ng * 16 + lr;
            const bf16x8 bh = *(const bf16x8*)&lB[0][br * 40 + lb * 8];
            const bf16x8 bl = *(const bf16x8*)&lB[1][br * 40 + lb * 8];
            acc[ng] = mfma16(ah, bh, acc[ng]);
            acc[ng] = mfma16(al, bh, acc[ng]);
            acc[ng] = mfma16(ah, bl, acc[ng]);
        }
        __syncthreads();
    }
    #pragma unroll
    for (int ng = 0; ng < 2; ++ng)
        #pragma unroll
        for (int i = 0; i < 4; ++i) {
            const int r = row0 + wq * 16 + lb * 4 + i;
            const int c = col0 + wn * 32 + ng * 16 + lr;
            out[(size_t)r * DM_ + c] = acc[ng][i];
        }
}

// ---------------------------------------------------------------------------
extern "C" void kernel_launch(void* const* d_in, const int* in_sizes, int n_in,
                              void* d_out, int out_size, void* d_ws, size_t ws_size,
                              hipStream_t stream) {
    const float* x      = (const float*)d_in[0];
    const float* logits = (const float*)d_in[1];
    float* out = (float*)d_out;

    char* p = (char*)d_ws;
    int* sel = (int*)p; p += 256;
    const size_t MB = 1024 * 1024;
    ush* Qh = (ush*)p; p += 2 * MB;
    ush* Ql = (ush*)p; p += 2 * MB;
    ush* Kh = (ush*)p; p += 2 * MB;
    ush* Kl = (ush*)p; p += 2 * MB;
    ush* Vth = (ush*)p; p += 2 * MB + 65536;   // pad: hd=8 garbage-row reads
    ush* Vtl = (ush*)p; p += 2 * MB + 65536;
    float* O = (float*)p; p += 4 * MB;
    ush* xh = (ush*)p; p += 2 * MB;
    ush* xl = (ush*)p; p += 2 * MB;
    ush* wqh = (ush*)p; p += 6 * MB;
    ush* wql = (ush*)p; p += 6 * MB;
    ush* woh = (ush*)p; p += 2 * MB;
    ush* wol = (ush*)p; p += 2 * MB;
    ush* Fh = xh, *Fl = xl;   // k_mix writes after k_qkv consumed xh/xl

    k_select<<<1, 64, 0, stream>>>(logits, sel);
    k_prep<<<dim3(2048), dim3(256), 0, stream>>>(
        sel, x,
        (const float*)d_in[2], (const float*)d_in[7],
        (const float*)d_in[12], (const float*)d_in[17],
        (const float*)d_in[3], (const float*)d_in[8],
        (const float*)d_in[13], (const float*)d_in[18],
        (const float*)d_in[4], (const float*)d_in[9],
        (const float*)d_in[14], (const float*)d_in[19],
        xh, xl, wqh, wql, woh, wol);
    k_qkv<<<dim3(768), dim3(256), 0, stream>>>(sel, xh, xl, wqh, wql,
                                               Qh, Ql, Kh, Kl, Vth, Vtl);
    k_attn<<<dim3(8192), dim3(256), 0, stream>>>(sel, Qh, Ql, Kh, Kl, Vth, Vtl, O);
    k_mix<<<dim3(B_ * N_ * DM_ / 256), dim3(256), 0, stream>>>(
        sel,
        (const float*)d_in[5],  (const float*)d_in[6],
        (const float*)d_in[10], (const float*)d_in[11],
        (const float*)d_in[15], (const float*)d_in[16],
        (const float*)d_in[20], (const float*)d_in[21],
        O, Fh, Fl);
    k_wo<<<dim3(512), dim3(256), 0, stream>>>(Fh, Fl, woh, wol, out);
}